// Round 4
// baseline (439.976 us; speedup 1.0000x reference)
//
#include <hip/hip_runtime.h>
#include <cstdint>
#include <cstddef>

#define B_SZ    200
#define NNZ_ALL 1070638
#define OUT_ALL 89064
#define NL      13
#define NB1     349   // ceil(OUT_ALL/256)
#define KL_IDX  93800 // 200*469, KL scalar position in d_out

__constant__ int c_nnz_off[NL + 1] = {0, 480000, 540000, 780000, 810000, 930000, 945000,
                                      1005000, 1012500, 1042500, 1046250, 1061258, 1063134, 1070638};
__constant__ int c_out_off[NL + 1] = {0, 30000, 45000, 60000, 67500, 75000, 78750,
                                      82500, 84375, 86250, 87188, 88126, 88595, 89064};

// ---------------- threefry2x32 (matches jax._src.prng) ----------------
__host__ __device__ inline void tf2x32(uint32_t k0, uint32_t k1, uint32_t& x0, uint32_t& x1) {
  uint32_t ks2 = k0 ^ k1 ^ 0x1BD11BDAu;
  x0 += k0; x1 += k1;
#define TF_ROT(v, d) (((v) << (d)) | ((v) >> (32 - (d))))
#define TF_R4(a, b, c, dd)                                   \
  { x0 += x1; x1 = TF_ROT(x1, a);  x1 ^= x0;                 \
    x0 += x1; x1 = TF_ROT(x1, b);  x1 ^= x0;                 \
    x0 += x1; x1 = TF_ROT(x1, c);  x1 ^= x0;                 \
    x0 += x1; x1 = TF_ROT(x1, dd); x1 ^= x0; }
  TF_R4(13, 15, 26, 6);  x0 += k1;  x1 += ks2 + 1u;
  TF_R4(17, 29, 16, 24); x0 += ks2; x1 += k0  + 2u;
  TF_R4(13, 15, 26, 6);  x0 += k0;  x1 += k1  + 3u;
  TF_R4(17, 29, 16, 24); x0 += k1;  x1 += ks2 + 4u;
  TF_R4(13, 15, 26, 6);  x0 += ks2; x1 += k0  + 5u;
#undef TF_R4
#undef TF_ROT
}

// partitionable threefry random bits for 32-bit: bits_i = o0 ^ o1, counter i (hi=0)
__device__ inline float jax_uniform01(uint32_t k0, uint32_t k1, uint32_t i) {
  uint32_t x0 = 0u, x1 = i;
  tf2x32(k0, k1, x0, x1);
  uint32_t bits = x0 ^ x1;
  return __uint_as_float((bits >> 9) | 0x3f800000u) - 1.0f;
}

// ---------------- transpose x (200 x 30000 row-major) -> xt (col-major, col stride 200)
// also zeroes the KL accumulator slot in d_out (runs before scatter on same stream)
__global__ void transpose_kernel(const float* __restrict__ x, float* __restrict__ xt,
                                 float* __restrict__ out_kl) {
  if (blockIdx.x == 0 && blockIdx.y == 0 && threadIdx.x == 0 && threadIdx.y == 0)
    out_kl[0] = 0.0f;
  __shared__ float tile[32][33];
  int s0 = blockIdx.x * 32;
  int b0 = blockIdx.y * 32;
#pragma unroll
  for (int j = 0; j < 4; ++j) {
    int b = b0 + threadIdx.y + j * 8;
    int s = s0 + threadIdx.x;
    if (b < B_SZ && s < 30000) tile[threadIdx.y + j * 8][threadIdx.x] = x[b * 30000 + s];
  }
  __syncthreads();
#pragma unroll
  for (int j = 0; j < 4; ++j) {
    int s = s0 + threadIdx.y + j * 8;
    int b = b0 + threadIdx.x;
    if (b < B_SZ && s < 30000) xt[s * B_SZ + b] = tile[threadIdx.x][threadIdx.y + j * 8];
  }
}

// ---------------- CSR build: histogram -> scan -> scatter (4B ids) -> expand ----------------
__device__ inline int edge_layer(int e) {
  int li = 0;
#pragma unroll
  for (int j = 1; j < NL; ++j) li += (e >= c_nnz_off[j]) ? 1 : 0;
  return li;
}

__global__ void hist_kernel(const int* __restrict__ dsts, int* __restrict__ counts) {
  int e = blockIdx.x * 256 + threadIdx.x;
  if (e >= NNZ_ALL) return;
  int li = edge_layer(e);
  atomicAdd(&counts[c_out_off[li] + dsts[e]], 1);
}

__global__ void scan1_kernel(const int* __restrict__ counts, int* __restrict__ ptr,
                             int* __restrict__ bsums) {
  __shared__ int sh[256];
  int t = threadIdx.x;
  int i = blockIdx.x * 256 + t;
  int v = (i < OUT_ALL) ? counts[i] : 0;
  sh[t] = v;
  __syncthreads();
  for (int o = 1; o < 256; o <<= 1) {
    int add = (t >= o) ? sh[t - o] : 0;
    __syncthreads();
    sh[t] += add;
    __syncthreads();
  }
  if (i < OUT_ALL) ptr[i] = sh[t] - v;          // exclusive within block
  if (t == 255) bsums[blockIdx.x] = sh[255];
}

__global__ void scan2_kernel(int* __restrict__ bsums) {
  __shared__ int sh[512];
  int t = threadIdx.x;
  int v = (t < NB1) ? bsums[t] : 0;
  sh[t] = v;
  __syncthreads();
  for (int o = 1; o < 512; o <<= 1) {
    int add = (t >= o) ? sh[t - o] : 0;
    __syncthreads();
    sh[t] += add;
    __syncthreads();
  }
  if (t < NB1) bsums[t] = sh[t] - v;            // exclusive block offsets
}

__global__ void scan3_kernel(int* __restrict__ ptr, const int* __restrict__ bsums,
                             int* __restrict__ cursor) {
  int i = blockIdx.x * 256 + threadIdx.x;
  if (i < OUT_ALL) {
    int p = ptr[i] + bsums[blockIdx.x];
    ptr[i] = p;
    cursor[i] = p;
  }
  if (i == 0) ptr[OUT_ALL] = NNZ_ALL;
}

// scatter 4-byte edge ids (normal cached store, L2 merges) + fused KL reduction
__global__ void scatter_kernel(const int* __restrict__ dsts,
                               const float* __restrict__ wmu, const float* __restrict__ wls,
                               int* __restrict__ cursor, int* __restrict__ idx,
                               float* __restrict__ out_kl) {
  int e = blockIdx.x * 256 + threadIdx.x;
  float kl = 0.f;
  if (e < NNZ_ALL) {
    int li = edge_layer(e);
    float m = wmu[e], l = wls[e];
    kl = expf(2.f * l) + m * m - 1.f - 2.f * l;
    int slot = atomicAdd(&cursor[c_out_off[li] + dsts[e]], 1);
    idx[slot] = e;
  }
  // block-reduce kl, one atomic per block
#pragma unroll
  for (int o = 32; o > 0; o >>= 1) kl += __shfl_down(kl, o, 64);
  __shared__ float sh[4];
  if ((threadIdx.x & 63) == 0) sh[threadIdx.x >> 6] = kl;
  __syncthreads();
  if (threadIdx.x == 0) {
    float s = sh[0] + sh[1] + sh[2] + sh[3];
    atomicAdd(out_kl, 0.5f * s);
  }
}

// expand: sequential read of idx, random 4B reads of srcs/wmu (L2-served),
// coalesced 8B writes of packed {src, w_bits} records
__global__ void expand_kernel(const int* __restrict__ idx, const int* __restrict__ srcs,
                              const float* __restrict__ wmu, int2* __restrict__ rec) {
  int i = blockIdx.x * 256 + threadIdx.x;
  if (i >= NNZ_ALL) return;
  int e = idx[i];
  rec[i] = make_int2(srcs[e], __float_as_int(wmu[e]));
}

// ---------------- pool layer (sparse gather + bias only) ----------------
// one block per output column; thread t<100 handles batch rows 2t, 2t+1 (float2)
__global__ __launch_bounds__(128) void pool_kernel(
    const float* __restrict__ hin, float* __restrict__ hout,
    const int* __restrict__ ptr, const int2* __restrict__ rec,
    const float* __restrict__ bias, int col_base) {
  const int d = blockIdx.x;
  const int t = threadIdx.x;
  if (t >= 100) return;
  const int g = col_base + d;
  int e0 = ptr[g], e1 = ptr[g + 1];
  const float2* __restrict__ hin2 = (const float2*)hin;
  float bb = bias[g];
  float a0 = bb, a1 = bb;
  int e = e0;
  for (; e + 2 <= e1; e += 2) {
    int2 rA = rec[e], rB = rec[e + 1];
    float wA = __int_as_float(rA.y), wB = __int_as_float(rB.y);
    float2 hA = hin2[rA.x * 100 + t];
    float2 hB = hin2[rB.x * 100 + t];
    a0 = fmaf(hA.x, wA, a0); a1 = fmaf(hA.y, wA, a1);
    a0 = fmaf(hB.x, wB, a0); a1 = fmaf(hB.y, wB, a1);
  }
  if (e < e1) {
    int2 rA = rec[e];
    float wA = __int_as_float(rA.y);
    float2 hA = hin2[rA.x * 100 + t];
    a0 = fmaf(hA.x, wA, a0); a1 = fmaf(hA.y, wA, a1);
  }
  ((float2*)hout)[d * 100 + t] = make_float2(a0, a1);
}

// ---------------- lin layer fused with BN + ReLU + dropout ----------------
__global__ __launch_bounds__(128) void lin_bn_drop_kernel(
    const float* __restrict__ hin, float* __restrict__ hout,
    const int* __restrict__ ptr, const int2* __restrict__ rec,
    const float* __restrict__ bias, const float* __restrict__ gamma, const float* __restrict__ beta,
    int col_base, int bn_base, int S, uint32_t k0, uint32_t k1) {
  const int d = blockIdx.x;
  const int t = threadIdx.x;
  const int g = col_base + d;
  const int e0 = ptr[g], e1 = ptr[g + 1];
  const float2* __restrict__ hin2 = (const float2*)hin;
  float a0 = 0.f, a1 = 0.f;
  if (t < 100) {
    int e = e0;
    for (; e + 2 <= e1; e += 2) {
      int2 rA = rec[e], rB = rec[e + 1];
      float wA = __int_as_float(rA.y), wB = __int_as_float(rB.y);
      float2 hA = hin2[rA.x * 100 + t];
      float2 hB = hin2[rB.x * 100 + t];
      a0 = fmaf(hA.x, wA, a0); a1 = fmaf(hA.y, wA, a1);
      a0 = fmaf(hB.x, wB, a0); a1 = fmaf(hB.y, wB, a1);
    }
    if (e < e1) {
      int2 rA = rec[e];
      float wA = __int_as_float(rA.y);
      float2 hA = hin2[rA.x * 100 + t];
      a0 = fmaf(hA.x, wA, a0); a1 = fmaf(hA.y, wA, a1);
    }
    float bb = bias[g];
    a0 += bb; a1 += bb;
  }
  // block reduce sum & sumsq over 200 values
  float s = a0 + a1;
  float q = a0 * a0 + a1 * a1;
#pragma unroll
  for (int o = 32; o > 0; o >>= 1) { s += __shfl_down(s, o, 64); q += __shfl_down(q, o, 64); }
  __shared__ float shs[2], shq[2];
  if ((t & 63) == 0) { shs[t >> 6] = s; shq[t >> 6] = q; }
  __syncthreads();
  float sum = shs[0] + shs[1];
  float ssq = shq[0] + shq[1];
  float m = sum * (1.0f / 200.0f);
  float v = ssq * (1.0f / 200.0f) - m * m;
  if (v < 0.f) v = 0.f;
  float rstd = 1.0f / sqrtf(v + 1e-5f);
  if (t < 100) {
    float ga = gamma[bn_base + d], be = beta[bn_base + d];
    float y0 = fmaf((a0 - m) * rstd, ga, be);
    float y1 = fmaf((a1 - m) * rstd, ga, be);
    y0 = y0 > 0.f ? y0 : 0.f;
    y1 = y1 > 0.f ? y1 : 0.f;
    // dropout: element index i = row*S + col, JAX partitionable threefry
    uint32_t i0 = (uint32_t)((2 * t) * S + d);
    float r0 = jax_uniform01(k0, k1, i0);
    float r1 = jax_uniform01(k0, k1, i0 + (uint32_t)S);
    y0 = (r0 < 0.9f) ? y0 * (1.0f / 0.9f) : 0.f;
    y1 = (r1 < 0.9f) ? y1 * (1.0f / 0.9f) : 0.f;
    ((float2*)hout)[d * 100 + t] = make_float2(y0, y1);
  }
}

// ---------------- final lin + plain BN, write row-major to d_out ----------------
__global__ __launch_bounds__(128) void final_bn_kernel(
    const float* __restrict__ hin, float* __restrict__ out,
    const int* __restrict__ ptr, const int2* __restrict__ rec,
    const float* __restrict__ bias, int col_base) {
  const int d = blockIdx.x;
  const int t = threadIdx.x;
  const int g = col_base + d;
  const int e0 = ptr[g], e1 = ptr[g + 1];
  const float2* __restrict__ hin2 = (const float2*)hin;
  float a0 = 0.f, a1 = 0.f;
  if (t < 100) {
    for (int e = e0; e < e1; ++e) {
      int2 rA = rec[e];
      float wA = __int_as_float(rA.y);
      float2 hA = hin2[rA.x * 100 + t];
      a0 = fmaf(hA.x, wA, a0); a1 = fmaf(hA.y, wA, a1);
    }
    float bb = bias[g];
    a0 += bb; a1 += bb;
  }
  float s = a0 + a1;
  float q = a0 * a0 + a1 * a1;
#pragma unroll
  for (int o = 32; o > 0; o >>= 1) { s += __shfl_down(s, o, 64); q += __shfl_down(q, o, 64); }
  __shared__ float shs[2], shq[2];
  if ((t & 63) == 0) { shs[t >> 6] = s; shq[t >> 6] = q; }
  __syncthreads();
  float sum = shs[0] + shs[1];
  float ssq = shq[0] + shq[1];
  float m = sum * (1.0f / 200.0f);
  float v = ssq * (1.0f / 200.0f) - m * m;
  if (v < 0.f) v = 0.f;
  float rstd = 1.0f / sqrtf(v + 1e-5f);
  if (t < 100) {
    out[(2 * t) * 469 + d]     = (a0 - m) * rstd;
    out[(2 * t + 1) * 469 + d] = (a1 - m) * rstd;
  }
}

extern "C" void kernel_launch(void* const* d_in, const int* in_sizes, int n_in,
                              void* d_out, int out_size, void* d_ws, size_t ws_size,
                              hipStream_t stream) {
  const float* x     = (const float*)d_in[0];
  const int*   edges = (const int*)d_in[1];
  const float* wmu   = (const float*)d_in[2];
  const float* wls   = (const float*)d_in[3];
  const float* bias  = (const float*)d_in[4];
  const float* gamma = (const float*)d_in[5];
  const float* beta  = (const float*)d_in[6];
  float* out = (float*)d_out;
  const int* srcs = edges;
  const int* dsts = edges + NNZ_ALL;

  char* p = (char*)d_ws;
  auto alloc = [&](size_t bytes) { char* r = p; p += (bytes + 255) & ~(size_t)255; return r; };
  float* A      = (float*)alloc((size_t)6000000 * 4);   // 30000 cols x 200
  float* Bf     = (float*)alloc((size_t)6000000 * 4);   // 30000 cols x 200
  float* C      = (float*)alloc((size_t)3000000 * 4);   // 15000 cols x 200 (pool outputs)
  int*   counts = (int*)alloc((size_t)OUT_ALL * 4);
  int*   ptr    = (int*)alloc((size_t)(OUT_ALL + 1) * 4);
  int*   cursor = (int*)alloc((size_t)OUT_ALL * 4);
  int*   bsums  = (int*)alloc((size_t)512 * 4);
  int*   idx    = (int*)alloc((size_t)NNZ_ALL * 4);
  int2*  rec    = (int2*)alloc((size_t)NNZ_ALL * 8);

  // stage dropout keys: fold_in(key(1234), 100+st) = threefry2x32((0,1234),(0,100+st))
  uint32_t k0s[6], k1s[6];
  for (int st = 0; st < 6; ++st) {
    uint32_t a = 0u, b = (uint32_t)(100 + st);
    tf2x32(0u, 1234u, a, b);
    k0s[st] = a; k1s[st] = b;
  }

  (void)hipMemsetAsync(counts, 0, (size_t)OUT_ALL * 4, stream);
  transpose_kernel<<<dim3(938, 7), dim3(32, 8), 0, stream>>>(x, A, out + KL_IDX);
  hist_kernel<<<(NNZ_ALL + 255) / 256, 256, 0, stream>>>(dsts, counts);
  scan1_kernel<<<NB1, 256, 0, stream>>>(counts, ptr, bsums);
  scan2_kernel<<<1, 512, 0, stream>>>(bsums);
  scan3_kernel<<<NB1, 256, 0, stream>>>(ptr, bsums, cursor);
  scatter_kernel<<<(NNZ_ALL + 255) / 256, 256, 0, stream>>>(dsts, wmu, wls, cursor, idx,
                                                            out + KL_IDX);
  expand_kernel<<<(NNZ_ALL + 255) / 256, 256, 0, stream>>>(idx, srcs, wmu, rec);

  const int S[7]       = {30000, 15000, 7500, 3750, 1875, 938, 469};
  const int OUT_OFF[14] = {0, 30000, 45000, 60000, 67500, 75000, 78750,
                           82500, 84375, 86250, 87188, 88126, 88595, 89064};
  const int BN_OFF[7]  = {0, 30000, 45000, 52500, 56250, 58125, 59063};

  // stage 0: lin layer 0 on x^T: A -> Bf (fused BN/ReLU/drop)
  lin_bn_drop_kernel<<<30000, 128, 0, stream>>>(A, Bf, ptr, rec, bias, gamma, beta,
                                                OUT_OFF[0], BN_OFF[0], S[0], k0s[0], k1s[0]);
  float* cur = Bf;
  float* alt = A;
  for (int st = 1; st <= 5; ++st) {
    int li_p = 2 * st - 1, li_l = 2 * st;
    pool_kernel<<<S[st], 128, 0, stream>>>(cur, C, ptr, rec, bias, OUT_OFF[li_p]);
    lin_bn_drop_kernel<<<S[st], 128, 0, stream>>>(C, alt, ptr, rec, bias, gamma, beta,
                                                  OUT_OFF[li_l], BN_OFF[st], S[st],
                                                  k0s[st], k1s[st]);
    float* tmp = cur; cur = alt; alt = tmp;
  }
  // stage 6: pool layer 11, then final lin 12 + plain BN -> d_out (row-major)
  pool_kernel<<<469, 128, 0, stream>>>(cur, C, ptr, rec, bias, OUT_OFF[11]);
  final_bn_kernel<<<469, 128, 0, stream>>>(C, out, ptr, rec, bias, OUT_OFF[12]);
}

// Round 5
// 432.600 us; speedup vs baseline: 1.0171x; 1.0171x over previous
//
#include <hip/hip_runtime.h>
#include <cstdint>
#include <cstddef>

#define B_SZ    200
#define NNZ_ALL 1070638
#define OUT_ALL 89064
#define NL      13
#define NB1     349   // ceil(OUT_ALL/256)
#define NCHUNK  4183  // ceil(NNZ_ALL/256)
#define KL_IDX  93800 // 200*469, KL scalar position in d_out

__constant__ int c_nnz_off[NL + 1] = {0, 480000, 540000, 780000, 810000, 930000, 945000,
                                      1005000, 1012500, 1042500, 1046250, 1061258, 1063134, 1070638};
__constant__ int c_out_off[NL + 1] = {0, 30000, 45000, 60000, 67500, 75000, 78750,
                                      82500, 84375, 86250, 87188, 88126, 88595, 89064};
__constant__ int c_sout[NL] = {30000, 15000, 15000, 7500, 7500, 3750, 3750,
                               1875, 1875, 938, 938, 469, 469};

// ---------------- threefry2x32 (matches jax._src.prng) ----------------
__host__ __device__ inline void tf2x32(uint32_t k0, uint32_t k1, uint32_t& x0, uint32_t& x1) {
  uint32_t ks2 = k0 ^ k1 ^ 0x1BD11BDAu;
  x0 += k0; x1 += k1;
#define TF_ROT(v, d) (((v) << (d)) | ((v) >> (32 - (d))))
#define TF_R4(a, b, c, dd)                                   \
  { x0 += x1; x1 = TF_ROT(x1, a);  x1 ^= x0;                 \
    x0 += x1; x1 = TF_ROT(x1, b);  x1 ^= x0;                 \
    x0 += x1; x1 = TF_ROT(x1, c);  x1 ^= x0;                 \
    x0 += x1; x1 = TF_ROT(x1, dd); x1 ^= x0; }
  TF_R4(13, 15, 26, 6);  x0 += k1;  x1 += ks2 + 1u;
  TF_R4(17, 29, 16, 24); x0 += ks2; x1 += k0  + 2u;
  TF_R4(13, 15, 26, 6);  x0 += k0;  x1 += k1  + 3u;
  TF_R4(17, 29, 16, 24); x0 += k1;  x1 += ks2 + 4u;
  TF_R4(13, 15, 26, 6);  x0 += ks2; x1 += k0  + 5u;
#undef TF_R4
#undef TF_ROT
}

// partitionable threefry random bits for 32-bit: bits_i = o0 ^ o1, counter i (hi=0)
__device__ inline float jax_uniform01(uint32_t k0, uint32_t k1, uint32_t i) {
  uint32_t x0 = 0u, x1 = i;
  tf2x32(k0, k1, x0, x1);
  uint32_t bits = x0 ^ x1;
  return __uint_as_float((bits >> 9) | 0x3f800000u) - 1.0f;
}

// ---------------- transpose x (200 x 30000 row-major) -> xt (col-major, col stride 200)
// also zeroes the KL accumulator slot in d_out (runs before scatter on same stream)
__global__ void transpose_kernel(const float* __restrict__ x, float* __restrict__ xt,
                                 float* __restrict__ out_kl) {
  if (blockIdx.x == 0 && blockIdx.y == 0 && threadIdx.x == 0 && threadIdx.y == 0)
    out_kl[0] = 0.0f;
  __shared__ float tile[32][33];
  int s0 = blockIdx.x * 32;
  int b0 = blockIdx.y * 32;
#pragma unroll
  for (int j = 0; j < 4; ++j) {
    int b = b0 + threadIdx.y + j * 8;
    int s = s0 + threadIdx.x;
    if (b < B_SZ && s < 30000) tile[threadIdx.y + j * 8][threadIdx.x] = x[b * 30000 + s];
  }
  __syncthreads();
#pragma unroll
  for (int j = 0; j < 4; ++j) {
    int s = s0 + threadIdx.y + j * 8;
    int b = b0 + threadIdx.x;
    if (b < B_SZ && s < 30000) xt[s * B_SZ + b] = tile[threadIdx.x][threadIdx.y + j * 8];
  }
}

// ---------------- CSR build: histogram -> scan -> partitioned scatter ----------------
__device__ inline int edge_layer(int e) {
  int li = 0;
#pragma unroll
  for (int j = 1; j < NL; ++j) li += (e >= c_nnz_off[j]) ? 1 : 0;
  return li;
}

// XCD-partitioned histogram: block (part, chunk); partition by dst slot range so each
// counts line is only dirtied by blocks with the same blockIdx%8 (-> same XCD, heuristically)
__global__ void hist_kernel(const int* __restrict__ dsts, int* __restrict__ counts) {
  const int part = blockIdx.x;                  // 0..7
  int e = blockIdx.y * 256 + threadIdx.x;
  if (e >= NNZ_ALL) return;
  int li = edge_layer(e);
  int dst = dsts[e];
  if ((dst * 8) / c_sout[li] == part)
    atomicAdd(&counts[c_out_off[li] + dst], 1);
}

__global__ void scan1_kernel(const int* __restrict__ counts, int* __restrict__ ptr,
                             int* __restrict__ bsums) {
  __shared__ int sh[256];
  int t = threadIdx.x;
  int i = blockIdx.x * 256 + t;
  int v = (i < OUT_ALL) ? counts[i] : 0;
  sh[t] = v;
  __syncthreads();
  for (int o = 1; o < 256; o <<= 1) {
    int add = (t >= o) ? sh[t - o] : 0;
    __syncthreads();
    sh[t] += add;
    __syncthreads();
  }
  if (i < OUT_ALL) ptr[i] = sh[t] - v;          // exclusive within block
  if (t == 255) bsums[blockIdx.x] = sh[255];
}

__global__ void scan2_kernel(int* __restrict__ bsums) {
  __shared__ int sh[512];
  int t = threadIdx.x;
  int v = (t < NB1) ? bsums[t] : 0;
  sh[t] = v;
  __syncthreads();
  for (int o = 1; o < 512; o <<= 1) {
    int add = (t >= o) ? sh[t - o] : 0;
    __syncthreads();
    sh[t] += add;
    __syncthreads();
  }
  if (t < NB1) bsums[t] = sh[t] - v;            // exclusive block offsets
}

__global__ void scan3_kernel(int* __restrict__ ptr, const int* __restrict__ bsums,
                             int* __restrict__ cursor) {
  int i = blockIdx.x * 256 + threadIdx.x;
  if (i < OUT_ALL) {
    int p = ptr[i] + bsums[blockIdx.x];
    ptr[i] = p;
    cursor[i] = p;
  }
  if (i == 0) ptr[OUT_ALL] = NNZ_ALL;
}

// XCD-partitioned scatter of packed {src, w_bits} records + fused KL (partition 0 only).
// An edge's slot lies in [ptr[g], ptr[g+1]) which is monotone in g, so partitioning by
// dst range partitions slot space into 8 contiguous ~1MB regions, each written by
// blocks of one blockIdx%8 class -> line-dense, single-XCD writes.
__global__ void scatter_kernel(const int* __restrict__ dsts, const int* __restrict__ srcs,
                               const float* __restrict__ wmu, const float* __restrict__ wls,
                               int* __restrict__ cursor, int2* __restrict__ rec,
                               float* __restrict__ out_kl) {
  const int part = blockIdx.x;                  // 0..7
  int e = blockIdx.y * 256 + threadIdx.x;
  float kl = 0.f;
  if (e < NNZ_ALL) {
    int li = edge_layer(e);
    int dst = dsts[e];
    if (part == 0) {
      float m = wmu[e], l = wls[e];
      kl = expf(2.f * l) + m * m - 1.f - 2.f * l;
    }
    if ((dst * 8) / c_sout[li] == part) {
      int slot = atomicAdd(&cursor[c_out_off[li] + dst], 1);
      rec[slot] = make_int2(srcs[e], __float_as_int(wmu[e]));
    }
  }
  if (part == 0) {
#pragma unroll
    for (int o = 32; o > 0; o >>= 1) kl += __shfl_down(kl, o, 64);
    __shared__ float sh[4];
    if ((threadIdx.x & 63) == 0) sh[threadIdx.x >> 6] = kl;
    __syncthreads();
    if (threadIdx.x == 0) {
      float s = sh[0] + sh[1] + sh[2] + sh[3];
      atomicAdd(out_kl, 0.5f * s);
    }
  }
}

// ---------------- pool layer (sparse gather + bias only) ----------------
// one block per output column; thread t<100 handles batch rows 2t, 2t+1 (float2)
__global__ __launch_bounds__(128) void pool_kernel(
    const float* __restrict__ hin, float* __restrict__ hout,
    const int* __restrict__ ptr, const int2* __restrict__ rec,
    const float* __restrict__ bias, int col_base) {
  const int d = blockIdx.x;
  const int t = threadIdx.x;
  if (t >= 100) return;
  const int g = col_base + d;
  int e0 = ptr[g], e1 = ptr[g + 1];
  const float2* __restrict__ hin2 = (const float2*)hin;
  float bb = bias[g];
  float a0 = bb, a1 = bb;
  int e = e0;
  for (; e + 2 <= e1; e += 2) {
    int2 rA = rec[e], rB = rec[e + 1];
    float wA = __int_as_float(rA.y), wB = __int_as_float(rB.y);
    float2 hA = hin2[rA.x * 100 + t];
    float2 hB = hin2[rB.x * 100 + t];
    a0 = fmaf(hA.x, wA, a0); a1 = fmaf(hA.y, wA, a1);
    a0 = fmaf(hB.x, wB, a0); a1 = fmaf(hB.y, wB, a1);
  }
  if (e < e1) {
    int2 rA = rec[e];
    float wA = __int_as_float(rA.y);
    float2 hA = hin2[rA.x * 100 + t];
    a0 = fmaf(hA.x, wA, a0); a1 = fmaf(hA.y, wA, a1);
  }
  ((float2*)hout)[d * 100 + t] = make_float2(a0, a1);
}

// ---------------- lin layer fused with BN + ReLU + dropout ----------------
__global__ __launch_bounds__(128) void lin_bn_drop_kernel(
    const float* __restrict__ hin, float* __restrict__ hout,
    const int* __restrict__ ptr, const int2* __restrict__ rec,
    const float* __restrict__ bias, const float* __restrict__ gamma, const float* __restrict__ beta,
    int col_base, int bn_base, int S, uint32_t k0, uint32_t k1) {
  const int d = blockIdx.x;
  const int t = threadIdx.x;
  const int g = col_base + d;
  const int e0 = ptr[g], e1 = ptr[g + 1];
  const float2* __restrict__ hin2 = (const float2*)hin;
  float a0 = 0.f, a1 = 0.f;
  if (t < 100) {
    int e = e0;
    for (; e + 2 <= e1; e += 2) {
      int2 rA = rec[e], rB = rec[e + 1];
      float wA = __int_as_float(rA.y), wB = __int_as_float(rB.y);
      float2 hA = hin2[rA.x * 100 + t];
      float2 hB = hin2[rB.x * 100 + t];
      a0 = fmaf(hA.x, wA, a0); a1 = fmaf(hA.y, wA, a1);
      a0 = fmaf(hB.x, wB, a0); a1 = fmaf(hB.y, wB, a1);
    }
    if (e < e1) {
      int2 rA = rec[e];
      float wA = __int_as_float(rA.y);
      float2 hA = hin2[rA.x * 100 + t];
      a0 = fmaf(hA.x, wA, a0); a1 = fmaf(hA.y, wA, a1);
    }
    float bb = bias[g];
    a0 += bb; a1 += bb;
  }
  // block reduce sum & sumsq over 200 values
  float s = a0 + a1;
  float q = a0 * a0 + a1 * a1;
#pragma unroll
  for (int o = 32; o > 0; o >>= 1) { s += __shfl_down(s, o, 64); q += __shfl_down(q, o, 64); }
  __shared__ float shs[2], shq[2];
  if ((t & 63) == 0) { shs[t >> 6] = s; shq[t >> 6] = q; }
  __syncthreads();
  float sum = shs[0] + shs[1];
  float ssq = shq[0] + shq[1];
  float m = sum * (1.0f / 200.0f);
  float v = ssq * (1.0f / 200.0f) - m * m;
  if (v < 0.f) v = 0.f;
  float rstd = 1.0f / sqrtf(v + 1e-5f);
  if (t < 100) {
    float ga = gamma[bn_base + d], be = beta[bn_base + d];
    float y0 = fmaf((a0 - m) * rstd, ga, be);
    float y1 = fmaf((a1 - m) * rstd, ga, be);
    y0 = y0 > 0.f ? y0 : 0.f;
    y1 = y1 > 0.f ? y1 : 0.f;
    // dropout: element index i = row*S + col, JAX partitionable threefry
    uint32_t i0 = (uint32_t)((2 * t) * S + d);
    float r0 = jax_uniform01(k0, k1, i0);
    float r1 = jax_uniform01(k0, k1, i0 + (uint32_t)S);
    y0 = (r0 < 0.9f) ? y0 * (1.0f / 0.9f) : 0.f;
    y1 = (r1 < 0.9f) ? y1 * (1.0f / 0.9f) : 0.f;
    ((float2*)hout)[d * 100 + t] = make_float2(y0, y1);
  }
}

// ---------------- final lin + plain BN, write row-major to d_out ----------------
__global__ __launch_bounds__(128) void final_bn_kernel(
    const float* __restrict__ hin, float* __restrict__ out,
    const int* __restrict__ ptr, const int2* __restrict__ rec,
    const float* __restrict__ bias, int col_base) {
  const int d = blockIdx.x;
  const int t = threadIdx.x;
  const int g = col_base + d;
  const int e0 = ptr[g], e1 = ptr[g + 1];
  const float2* __restrict__ hin2 = (const float2*)hin;
  float a0 = 0.f, a1 = 0.f;
  if (t < 100) {
    for (int e = e0; e < e1; ++e) {
      int2 rA = rec[e];
      float wA = __int_as_float(rA.y);
      float2 hA = hin2[rA.x * 100 + t];
      a0 = fmaf(hA.x, wA, a0); a1 = fmaf(hA.y, wA, a1);
    }
    float bb = bias[g];
    a0 += bb; a1 += bb;
  }
  float s = a0 + a1;
  float q = a0 * a0 + a1 * a1;
#pragma unroll
  for (int o = 32; o > 0; o >>= 1) { s += __shfl_down(s, o, 64); q += __shfl_down(q, o, 64); }
  __shared__ float shs[2], shq[2];
  if ((t & 63) == 0) { shs[t >> 6] = s; shq[t >> 6] = q; }
  __syncthreads();
  float sum = shs[0] + shs[1];
  float ssq = shq[0] + shq[1];
  float m = sum * (1.0f / 200.0f);
  float v = ssq * (1.0f / 200.0f) - m * m;
  if (v < 0.f) v = 0.f;
  float rstd = 1.0f / sqrtf(v + 1e-5f);
  if (t < 100) {
    out[(2 * t) * 469 + d]     = (a0 - m) * rstd;
    out[(2 * t + 1) * 469 + d] = (a1 - m) * rstd;
  }
}

extern "C" void kernel_launch(void* const* d_in, const int* in_sizes, int n_in,
                              void* d_out, int out_size, void* d_ws, size_t ws_size,
                              hipStream_t stream) {
  const float* x     = (const float*)d_in[0];
  const int*   edges = (const int*)d_in[1];
  const float* wmu   = (const float*)d_in[2];
  const float* wls   = (const float*)d_in[3];
  const float* bias  = (const float*)d_in[4];
  const float* gamma = (const float*)d_in[5];
  const float* beta  = (const float*)d_in[6];
  float* out = (float*)d_out;
  const int* srcs = edges;
  const int* dsts = edges + NNZ_ALL;

  char* p = (char*)d_ws;
  auto alloc = [&](size_t bytes) { char* r = p; p += (bytes + 255) & ~(size_t)255; return r; };
  float* A      = (float*)alloc((size_t)6000000 * 4);   // 30000 cols x 200
  float* Bf     = (float*)alloc((size_t)6000000 * 4);   // 30000 cols x 200
  float* C      = (float*)alloc((size_t)3000000 * 4);   // 15000 cols x 200 (pool outputs)
  int*   counts = (int*)alloc((size_t)OUT_ALL * 4);
  int*   ptr    = (int*)alloc((size_t)(OUT_ALL + 1) * 4);
  int*   cursor = (int*)alloc((size_t)OUT_ALL * 4);
  int*   bsums  = (int*)alloc((size_t)512 * 4);
  int2*  rec    = (int2*)alloc((size_t)NNZ_ALL * 8);

  // stage dropout keys: fold_in(key(1234), 100+st) = threefry2x32((0,1234),(0,100+st))
  uint32_t k0s[6], k1s[6];
  for (int st = 0; st < 6; ++st) {
    uint32_t a = 0u, b = (uint32_t)(100 + st);
    tf2x32(0u, 1234u, a, b);
    k0s[st] = a; k1s[st] = b;
  }

  (void)hipMemsetAsync(counts, 0, (size_t)OUT_ALL * 4, stream);
  transpose_kernel<<<dim3(938, 7), dim3(32, 8), 0, stream>>>(x, A, out + KL_IDX);
  hist_kernel<<<dim3(8, NCHUNK), 256, 0, stream>>>(dsts, counts);
  scan1_kernel<<<NB1, 256, 0, stream>>>(counts, ptr, bsums);
  scan2_kernel<<<1, 512, 0, stream>>>(bsums);
  scan3_kernel<<<NB1, 256, 0, stream>>>(ptr, bsums, cursor);
  scatter_kernel<<<dim3(8, NCHUNK), 256, 0, stream>>>(dsts, srcs, wmu, wls, cursor, rec,
                                                      out + KL_IDX);

  const int S[7]       = {30000, 15000, 7500, 3750, 1875, 938, 469};
  const int OUT_OFF[14] = {0, 30000, 45000, 60000, 67500, 75000, 78750,
                           82500, 84375, 86250, 87188, 88126, 88595, 89064};
  const int BN_OFF[7]  = {0, 30000, 45000, 52500, 56250, 58125, 59063};

  // stage 0: lin layer 0 on x^T: A -> Bf (fused BN/ReLU/drop)
  lin_bn_drop_kernel<<<30000, 128, 0, stream>>>(A, Bf, ptr, rec, bias, gamma, beta,
                                                OUT_OFF[0], BN_OFF[0], S[0], k0s[0], k1s[0]);
  float* cur = Bf;
  float* alt = A;
  for (int st = 1; st <= 5; ++st) {
    int li_p = 2 * st - 1, li_l = 2 * st;
    pool_kernel<<<S[st], 128, 0, stream>>>(cur, C, ptr, rec, bias, OUT_OFF[li_p]);
    lin_bn_drop_kernel<<<S[st], 128, 0, stream>>>(C, alt, ptr, rec, bias, gamma, beta,
                                                  OUT_OFF[li_l], BN_OFF[st], S[st],
                                                  k0s[st], k1s[st]);
    float* tmp = cur; cur = alt; alt = tmp;
  }
  // stage 6: pool layer 11, then final lin 12 + plain BN -> d_out (row-major)
  pool_kernel<<<469, 128, 0, stream>>>(cur, C, ptr, rec, bias, OUT_OFF[11]);
  final_bn_kernel<<<469, 128, 0, stream>>>(C, out, ptr, rec, bias, OUT_OFF[12]);
}

// Round 6
// 337.770 us; speedup vs baseline: 1.3026x; 1.2808x over previous
//
#include <hip/hip_runtime.h>
#include <cstdint>
#include <cstddef>

#define B_SZ    200
#define NNZ_ALL 1070638
#define OUT_ALL 89064
#define NL      13
#define NBUCK   696    // ceil(OUT_ALL/128) slot-space buckets of 128 columns
#define EPB     8192   // edges per block in p1/p3
#define NBLK    131    // ceil(NNZ_ALL/EPB)
#define NSCAN   91176  // NBUCK*NBLK
#define NSB     357    // ceil(NSCAN/256)
#define KL_IDX  93800  // 200*469, KL scalar position in d_out

__constant__ int c_nnz_off[NL + 1] = {0, 480000, 540000, 780000, 810000, 930000, 945000,
                                      1005000, 1012500, 1042500, 1046250, 1061258, 1063134, 1070638};
__constant__ int c_out_off[NL + 1] = {0, 30000, 45000, 60000, 67500, 75000, 78750,
                                      82500, 84375, 86250, 87188, 88126, 88595, 89064};

// ---------------- threefry2x32 (matches jax._src.prng) ----------------
__host__ __device__ inline void tf2x32(uint32_t k0, uint32_t k1, uint32_t& x0, uint32_t& x1) {
  uint32_t ks2 = k0 ^ k1 ^ 0x1BD11BDAu;
  x0 += k0; x1 += k1;
#define TF_ROT(v, d) (((v) << (d)) | ((v) >> (32 - (d))))
#define TF_R4(a, b, c, dd)                                   \
  { x0 += x1; x1 = TF_ROT(x1, a);  x1 ^= x0;                 \
    x0 += x1; x1 = TF_ROT(x1, b);  x1 ^= x0;                 \
    x0 += x1; x1 = TF_ROT(x1, c);  x1 ^= x0;                 \
    x0 += x1; x1 = TF_ROT(x1, dd); x1 ^= x0; }
  TF_R4(13, 15, 26, 6);  x0 += k1;  x1 += ks2 + 1u;
  TF_R4(17, 29, 16, 24); x0 += ks2; x1 += k0  + 2u;
  TF_R4(13, 15, 26, 6);  x0 += k0;  x1 += k1  + 3u;
  TF_R4(17, 29, 16, 24); x0 += k1;  x1 += ks2 + 4u;
  TF_R4(13, 15, 26, 6);  x0 += ks2; x1 += k0  + 5u;
#undef TF_R4
#undef TF_ROT
}

// partitionable threefry random bits for 32-bit: bits_i = o0 ^ o1, counter i (hi=0)
__device__ inline float jax_uniform01(uint32_t k0, uint32_t k1, uint32_t i) {
  uint32_t x0 = 0u, x1 = i;
  tf2x32(k0, k1, x0, x1);
  uint32_t bits = x0 ^ x1;
  return __uint_as_float((bits >> 9) | 0x3f800000u) - 1.0f;
}

// ---------------- transpose x (200 x 30000 row-major) -> xt (col-major, col stride 200)
// also zeroes the KL accumulator slot in d_out
__global__ void transpose_kernel(const float* __restrict__ x, float* __restrict__ xt,
                                 float* __restrict__ out_kl) {
  if (blockIdx.x == 0 && blockIdx.y == 0 && threadIdx.x == 0 && threadIdx.y == 0)
    out_kl[0] = 0.0f;
  __shared__ float tile[32][33];
  int s0 = blockIdx.x * 32;
  int b0 = blockIdx.y * 32;
#pragma unroll
  for (int j = 0; j < 4; ++j) {
    int b = b0 + threadIdx.y + j * 8;
    int s = s0 + threadIdx.x;
    if (b < B_SZ && s < 30000) tile[threadIdx.y + j * 8][threadIdx.x] = x[b * 30000 + s];
  }
  __syncthreads();
#pragma unroll
  for (int j = 0; j < 4; ++j) {
    int s = s0 + threadIdx.y + j * 8;
    int b = b0 + threadIdx.x;
    if (b < B_SZ && s < 30000) xt[s * B_SZ + b] = tile[threadIdx.x][threadIdx.y + j * 8];
  }
}

__device__ inline int edge_layer(int e) {
  int li = 0;
#pragma unroll
  for (int j = 1; j < NL; ++j) li += (e >= c_nnz_off[j]) ? 1 : 0;
  return li;
}

// ---------------- CSR build v2: chunked counting sort, no global atomics ----------------
// p1: per-(block,bucket) LDS histogram -> hist[bucket*NBLK + block]
__global__ __launch_bounds__(256) void p1_kernel(const int* __restrict__ dsts,
                                                 int* __restrict__ hist) {
  __shared__ int cnt[NBUCK];
  for (int j = threadIdx.x; j < NBUCK; j += 256) cnt[j] = 0;
  __syncthreads();
  int e0 = blockIdx.x * EPB;
  int e1 = min(e0 + EPB, NNZ_ALL);
  for (int e = e0 + threadIdx.x; e < e1; e += 256) {
    int li = edge_layer(e);
    int gcol = c_out_off[li] + dsts[e];
    atomicAdd(&cnt[gcol >> 7], 1);
  }
  __syncthreads();
  for (int j = threadIdx.x; j < NBUCK; j += 256) hist[j * NBLK + blockIdx.x] = cnt[j];
}

// 3-phase exclusive scan over hist[NSCAN] -> start[NSCAN]
__global__ void scanA_kernel(const int* __restrict__ hist, int* __restrict__ start,
                             int* __restrict__ bsums) {
  __shared__ int sh[256];
  int t = threadIdx.x;
  int i = blockIdx.x * 256 + t;
  int v = (i < NSCAN) ? hist[i] : 0;
  sh[t] = v;
  __syncthreads();
  for (int o = 1; o < 256; o <<= 1) {
    int add = (t >= o) ? sh[t - o] : 0;
    __syncthreads();
    sh[t] += add;
    __syncthreads();
  }
  if (i < NSCAN) start[i] = sh[t] - v;
  if (t == 255) bsums[blockIdx.x] = sh[255];
}

__global__ void scanB_kernel(int* __restrict__ bsums) {
  __shared__ int sh[512];
  int t = threadIdx.x;
  int v = (t < NSB) ? bsums[t] : 0;
  sh[t] = v;
  __syncthreads();
  for (int o = 1; o < 512; o <<= 1) {
    int add = (t >= o) ? sh[t - o] : 0;
    __syncthreads();
    sh[t] += add;
    __syncthreads();
  }
  if (t < NSB) bsums[t] = sh[t] - v;
}

__global__ void scanC_kernel(int* __restrict__ start, const int* __restrict__ bsums) {
  int i = blockIdx.x * 256 + threadIdx.x;
  if (i < NSCAN) start[i] += bsums[blockIdx.x];
}

// p3: place edges into private (block,bucket) staging sub-ranges via LDS cursors.
// staging entry: .x = w bits, .y = (src<<7) | (gcol&127). KL fused.
__global__ __launch_bounds__(256) void p3_kernel(
    const int* __restrict__ dsts, const int* __restrict__ srcs,
    const float* __restrict__ wmu, const float* __restrict__ wls,
    const int* __restrict__ start, int2* __restrict__ staging, float* __restrict__ out_kl) {
  __shared__ int cur[NBUCK];
  for (int j = threadIdx.x; j < NBUCK; j += 256) cur[j] = start[j * NBLK + blockIdx.x];
  __syncthreads();
  int e0 = blockIdx.x * EPB;
  int e1 = min(e0 + EPB, NNZ_ALL);
  float kl = 0.f;
  for (int e = e0 + threadIdx.x; e < e1; e += 256) {
    int li = edge_layer(e);
    int gcol = c_out_off[li] + dsts[e];
    float m = wmu[e], l = wls[e];
    kl += expf(2.f * l) + m * m - 1.f - 2.f * l;
    int pos = atomicAdd(&cur[gcol >> 7], 1);
    staging[pos] = make_int2(__float_as_int(m), (srcs[e] << 7) | (gcol & 127));
  }
#pragma unroll
  for (int o = 32; o > 0; o >>= 1) kl += __shfl_down(kl, o, 64);
  __shared__ float sh[4];
  if ((threadIdx.x & 63) == 0) sh[threadIdx.x >> 6] = kl;
  __syncthreads();
  if (threadIdx.x == 0) atomicAdd(out_kl, 0.5f * (sh[0] + sh[1] + sh[2] + sh[3]));
}

// finalize: per bucket, count columns, write ptr[], reorder staging -> rec {src, w}
__global__ __launch_bounds__(256) void fin_kernel(const int* __restrict__ start,
                                                  const int2* __restrict__ staging,
                                                  int2* __restrict__ rec, int* __restrict__ ptr) {
  int b = blockIdx.x;
  int base = start[b * NBLK];
  int end = (b + 1 < NBUCK) ? start[(b + 1) * NBLK] : NNZ_ALL;
  int colbase = b << 7;
  int ncols = min(128, OUT_ALL - colbase);
  __shared__ int cnt[128], sc[128], cur[128];
  int t = threadIdx.x;
  if (t < 128) cnt[t] = 0;
  __syncthreads();
  for (int i = base + t; i < end; i += 256) atomicAdd(&cnt[staging[i].y & 127], 1);
  __syncthreads();
  if (t < 128) sc[t] = cnt[t];
  __syncthreads();
  for (int o = 1; o < 128; o <<= 1) {
    int add = (t < 128 && t >= o) ? sc[t - o] : 0;
    __syncthreads();
    if (t < 128) sc[t] += add;
    __syncthreads();
  }
  if (t < 128) {
    int excl = base + sc[t] - cnt[t];
    cur[t] = excl;
    if (t < ncols) ptr[colbase + t] = excl;
  }
  if (b == NBUCK - 1 && t == 0) ptr[OUT_ALL] = NNZ_ALL;
  __syncthreads();
  for (int i = base + t; i < end; i += 256) {
    int2 v = staging[i];
    int p = atomicAdd(&cur[v.y & 127], 1);
    rec[p] = make_int2(v.y >> 7, v.x);
  }
}

// ---------------- pool layer (sparse gather + bias only) ----------------
__global__ __launch_bounds__(128) void pool_kernel(
    const float* __restrict__ hin, float* __restrict__ hout,
    const int* __restrict__ ptr, const int2* __restrict__ rec,
    const float* __restrict__ bias, int col_base) {
  const int d = blockIdx.x;
  const int t = threadIdx.x;
  if (t >= 100) return;
  const int g = col_base + d;
  int e0 = ptr[g], e1 = ptr[g + 1];
  const float2* __restrict__ hin2 = (const float2*)hin;
  float bb = bias[g];
  float a0 = bb, a1 = bb;
  int e = e0;
  for (; e + 2 <= e1; e += 2) {
    int2 rA = rec[e], rB = rec[e + 1];
    float wA = __int_as_float(rA.y), wB = __int_as_float(rB.y);
    float2 hA = hin2[rA.x * 100 + t];
    float2 hB = hin2[rB.x * 100 + t];
    a0 = fmaf(hA.x, wA, a0); a1 = fmaf(hA.y, wA, a1);
    a0 = fmaf(hB.x, wB, a0); a1 = fmaf(hB.y, wB, a1);
  }
  if (e < e1) {
    int2 rA = rec[e];
    float wA = __int_as_float(rA.y);
    float2 hA = hin2[rA.x * 100 + t];
    a0 = fmaf(hA.x, wA, a0); a1 = fmaf(hA.y, wA, a1);
  }
  ((float2*)hout)[d * 100 + t] = make_float2(a0, a1);
}

// ---------------- lin layer fused with BN + ReLU + dropout ----------------
__global__ __launch_bounds__(128) void lin_bn_drop_kernel(
    const float* __restrict__ hin, float* __restrict__ hout,
    const int* __restrict__ ptr, const int2* __restrict__ rec,
    const float* __restrict__ bias, const float* __restrict__ gamma, const float* __restrict__ beta,
    int col_base, int bn_base, int S, uint32_t k0, uint32_t k1) {
  const int d = blockIdx.x;
  const int t = threadIdx.x;
  const int g = col_base + d;
  const int e0 = ptr[g], e1 = ptr[g + 1];
  const float2* __restrict__ hin2 = (const float2*)hin;
  float a0 = 0.f, a1 = 0.f;
  if (t < 100) {
    int e = e0;
    for (; e + 2 <= e1; e += 2) {
      int2 rA = rec[e], rB = rec[e + 1];
      float wA = __int_as_float(rA.y), wB = __int_as_float(rB.y);
      float2 hA = hin2[rA.x * 100 + t];
      float2 hB = hin2[rB.x * 100 + t];
      a0 = fmaf(hA.x, wA, a0); a1 = fmaf(hA.y, wA, a1);
      a0 = fmaf(hB.x, wB, a0); a1 = fmaf(hB.y, wB, a1);
    }
    if (e < e1) {
      int2 rA = rec[e];
      float wA = __int_as_float(rA.y);
      float2 hA = hin2[rA.x * 100 + t];
      a0 = fmaf(hA.x, wA, a0); a1 = fmaf(hA.y, wA, a1);
    }
    float bb = bias[g];
    a0 += bb; a1 += bb;
  }
  float s = a0 + a1;
  float q = a0 * a0 + a1 * a1;
#pragma unroll
  for (int o = 32; o > 0; o >>= 1) { s += __shfl_down(s, o, 64); q += __shfl_down(q, o, 64); }
  __shared__ float shs[2], shq[2];
  if ((t & 63) == 0) { shs[t >> 6] = s; shq[t >> 6] = q; }
  __syncthreads();
  float sum = shs[0] + shs[1];
  float ssq = shq[0] + shq[1];
  float m = sum * (1.0f / 200.0f);
  float v = ssq * (1.0f / 200.0f) - m * m;
  if (v < 0.f) v = 0.f;
  float rstd = 1.0f / sqrtf(v + 1e-5f);
  if (t < 100) {
    float ga = gamma[bn_base + d], be = beta[bn_base + d];
    float y0 = fmaf((a0 - m) * rstd, ga, be);
    float y1 = fmaf((a1 - m) * rstd, ga, be);
    y0 = y0 > 0.f ? y0 : 0.f;
    y1 = y1 > 0.f ? y1 : 0.f;
    uint32_t i0 = (uint32_t)((2 * t) * S + d);
    float r0 = jax_uniform01(k0, k1, i0);
    float r1 = jax_uniform01(k0, k1, i0 + (uint32_t)S);
    y0 = (r0 < 0.9f) ? y0 * (1.0f / 0.9f) : 0.f;
    y1 = (r1 < 0.9f) ? y1 * (1.0f / 0.9f) : 0.f;
    ((float2*)hout)[d * 100 + t] = make_float2(y0, y1);
  }
}

// ---------------- final lin + plain BN, write row-major to d_out ----------------
__global__ __launch_bounds__(128) void final_bn_kernel(
    const float* __restrict__ hin, float* __restrict__ out,
    const int* __restrict__ ptr, const int2* __restrict__ rec,
    const float* __restrict__ bias, int col_base) {
  const int d = blockIdx.x;
  const int t = threadIdx.x;
  const int g = col_base + d;
  const int e0 = ptr[g], e1 = ptr[g + 1];
  const float2* __restrict__ hin2 = (const float2*)hin;
  float a0 = 0.f, a1 = 0.f;
  if (t < 100) {
    for (int e = e0; e < e1; ++e) {
      int2 rA = rec[e];
      float wA = __int_as_float(rA.y);
      float2 hA = hin2[rA.x * 100 + t];
      a0 = fmaf(hA.x, wA, a0); a1 = fmaf(hA.y, wA, a1);
    }
    float bb = bias[g];
    a0 += bb; a1 += bb;
  }
  float s = a0 + a1;
  float q = a0 * a0 + a1 * a1;
#pragma unroll
  for (int o = 32; o > 0; o >>= 1) { s += __shfl_down(s, o, 64); q += __shfl_down(q, o, 64); }
  __shared__ float shs[2], shq[2];
  if ((t & 63) == 0) { shs[t >> 6] = s; shq[t >> 6] = q; }
  __syncthreads();
  float sum = shs[0] + shs[1];
  float ssq = shq[0] + shq[1];
  float m = sum * (1.0f / 200.0f);
  float v = ssq * (1.0f / 200.0f) - m * m;
  if (v < 0.f) v = 0.f;
  float rstd = 1.0f / sqrtf(v + 1e-5f);
  if (t < 100) {
    out[(2 * t) * 469 + d]     = (a0 - m) * rstd;
    out[(2 * t + 1) * 469 + d] = (a1 - m) * rstd;
  }
}

extern "C" void kernel_launch(void* const* d_in, const int* in_sizes, int n_in,
                              void* d_out, int out_size, void* d_ws, size_t ws_size,
                              hipStream_t stream) {
  const float* x     = (const float*)d_in[0];
  const int*   edges = (const int*)d_in[1];
  const float* wmu   = (const float*)d_in[2];
  const float* wls   = (const float*)d_in[3];
  const float* bias  = (const float*)d_in[4];
  const float* gamma = (const float*)d_in[5];
  const float* beta  = (const float*)d_in[6];
  float* out = (float*)d_out;
  const int* srcs = edges;
  const int* dsts = edges + NNZ_ALL;

  char* p = (char*)d_ws;
  auto alloc = [&](size_t bytes) { char* r = p; p += (bytes + 255) & ~(size_t)255; return r; };
  float* A       = (float*)alloc((size_t)6000000 * 4);   // 30000 cols x 200
  float* Bf      = (float*)alloc((size_t)6000000 * 4);   // 30000 cols x 200
  float* C       = (float*)alloc((size_t)3000000 * 4);   // 15000 cols x 200 (pool outputs)
  int*   ptr     = (int*)alloc((size_t)(OUT_ALL + 1) * 4);
  int*   hist    = (int*)alloc((size_t)NSCAN * 4);
  int*   start   = (int*)alloc((size_t)NSCAN * 4);
  int*   bsums   = (int*)alloc((size_t)512 * 4);
  int2*  staging = (int2*)alloc((size_t)NNZ_ALL * 8);
  int2*  rec     = (int2*)alloc((size_t)NNZ_ALL * 8);

  // stage dropout keys: fold_in(key(1234), 100+st) = threefry2x32((0,1234),(0,100+st))
  uint32_t k0s[6], k1s[6];
  for (int st = 0; st < 6; ++st) {
    uint32_t a = 0u, b = (uint32_t)(100 + st);
    tf2x32(0u, 1234u, a, b);
    k0s[st] = a; k1s[st] = b;
  }

  transpose_kernel<<<dim3(938, 7), dim3(32, 8), 0, stream>>>(x, A, out + KL_IDX);
  p1_kernel<<<NBLK, 256, 0, stream>>>(dsts, hist);
  scanA_kernel<<<NSB, 256, 0, stream>>>(hist, start, bsums);
  scanB_kernel<<<1, 512, 0, stream>>>(bsums);
  scanC_kernel<<<NSB, 256, 0, stream>>>(start, bsums);
  p3_kernel<<<NBLK, 256, 0, stream>>>(dsts, srcs, wmu, wls, start, staging, out + KL_IDX);
  fin_kernel<<<NBUCK, 256, 0, stream>>>(start, staging, rec, ptr);

  const int S[7]        = {30000, 15000, 7500, 3750, 1875, 938, 469};
  const int OUT_OFF[14] = {0, 30000, 45000, 60000, 67500, 75000, 78750,
                           82500, 84375, 86250, 87188, 88126, 88595, 89064};
  const int BN_OFF[7]   = {0, 30000, 45000, 52500, 56250, 58125, 59063};

  lin_bn_drop_kernel<<<30000, 128, 0, stream>>>(A, Bf, ptr, rec, bias, gamma, beta,
                                                OUT_OFF[0], BN_OFF[0], S[0], k0s[0], k1s[0]);
  float* cur = Bf;
  float* alt = A;
  for (int st = 1; st <= 5; ++st) {
    int li_p = 2 * st - 1, li_l = 2 * st;
    pool_kernel<<<S[st], 128, 0, stream>>>(cur, C, ptr, rec, bias, OUT_OFF[li_p]);
    lin_bn_drop_kernel<<<S[st], 128, 0, stream>>>(C, alt, ptr, rec, bias, gamma, beta,
                                                  OUT_OFF[li_l], BN_OFF[st], S[st],
                                                  k0s[st], k1s[st]);
    float* tmp = cur; cur = alt; alt = tmp;
  }
  pool_kernel<<<469, 128, 0, stream>>>(cur, C, ptr, rec, bias, OUT_OFF[11]);
  final_bn_kernel<<<469, 128, 0, stream>>>(C, out, ptr, rec, bias, OUT_OFF[12]);
}

// Round 7
// 314.448 us; speedup vs baseline: 1.3992x; 1.0742x over previous
//
#include <hip/hip_runtime.h>
#include <hip/hip_fp16.h>
#include <cstdint>
#include <cstddef>

#define B_SZ    200
#define NNZ_ALL 1070638
#define OUT_ALL 89064
#define NL      13
#define NBUCK   696    // ceil(OUT_ALL/128) slot-space buckets of 128 columns
#define EPB     8192   // edges per block in p1/p3
#define NBLK    131    // ceil(NNZ_ALL/EPB)
#define NSCAN   91176  // NBUCK*NBLK
#define NSB     357    // ceil(NSCAN/256)
#define KL_IDX  93800  // 200*469, KL scalar position in d_out

__constant__ int c_nnz_off[NL + 1] = {0, 480000, 540000, 780000, 810000, 930000, 945000,
                                      1005000, 1012500, 1042500, 1046250, 1061258, 1063134, 1070638};
__constant__ int c_out_off[NL + 1] = {0, 30000, 45000, 60000, 67500, 75000, 78750,
                                      82500, 84375, 86250, 87188, 88126, 88595, 89064};

// ---------------- threefry2x32 (matches jax._src.prng) ----------------
__host__ __device__ inline void tf2x32(uint32_t k0, uint32_t k1, uint32_t& x0, uint32_t& x1) {
  uint32_t ks2 = k0 ^ k1 ^ 0x1BD11BDAu;
  x0 += k0; x1 += k1;
#define TF_ROT(v, d) (((v) << (d)) | ((v) >> (32 - (d))))
#define TF_R4(a, b, c, dd)                                   \
  { x0 += x1; x1 = TF_ROT(x1, a);  x1 ^= x0;                 \
    x0 += x1; x1 = TF_ROT(x1, b);  x1 ^= x0;                 \
    x0 += x1; x1 = TF_ROT(x1, c);  x1 ^= x0;                 \
    x0 += x1; x1 = TF_ROT(x1, dd); x1 ^= x0; }
  TF_R4(13, 15, 26, 6);  x0 += k1;  x1 += ks2 + 1u;
  TF_R4(17, 29, 16, 24); x0 += ks2; x1 += k0  + 2u;
  TF_R4(13, 15, 26, 6);  x0 += k0;  x1 += k1  + 3u;
  TF_R4(17, 29, 16, 24); x0 += k1;  x1 += ks2 + 4u;
  TF_R4(13, 15, 26, 6);  x0 += ks2; x1 += k0  + 5u;
#undef TF_R4
#undef TF_ROT
}

// partitionable threefry random bits for 32-bit: bits_i = o0 ^ o1, counter i (hi=0)
__device__ inline float jax_uniform01(uint32_t k0, uint32_t k1, uint32_t i) {
  uint32_t x0 = 0u, x1 = i;
  tf2x32(k0, k1, x0, x1);
  uint32_t bits = x0 ^ x1;
  return __uint_as_float((bits >> 9) | 0x3f800000u) - 1.0f;
}

// ---------------- transpose x (200 x 30000 fp32 row-major) -> xt (fp16 col-major, stride 200)
// also zeroes the KL accumulator slot in d_out
__global__ void transpose_kernel(const float* __restrict__ x, __half* __restrict__ xt,
                                 float* __restrict__ out_kl) {
  if (blockIdx.x == 0 && blockIdx.y == 0 && threadIdx.x == 0 && threadIdx.y == 0)
    out_kl[0] = 0.0f;
  __shared__ float tile[32][33];
  int s0 = blockIdx.x * 32;
  int b0 = blockIdx.y * 32;
#pragma unroll
  for (int j = 0; j < 4; ++j) {
    int b = b0 + threadIdx.y + j * 8;
    int s = s0 + threadIdx.x;
    if (b < B_SZ && s < 30000) tile[threadIdx.y + j * 8][threadIdx.x] = x[b * 30000 + s];
  }
  __syncthreads();
#pragma unroll
  for (int j = 0; j < 4; ++j) {
    int s = s0 + threadIdx.y + j * 8;
    int b = b0 + threadIdx.x;
    if (b < B_SZ && s < 30000) xt[s * B_SZ + b] = __float2half(tile[threadIdx.x][threadIdx.y + j * 8]);
  }
}

__device__ inline int edge_layer(int e) {
  int li = 0;
#pragma unroll
  for (int j = 1; j < NL; ++j) li += (e >= c_nnz_off[j]) ? 1 : 0;
  return li;
}

// ---------------- CSR build: chunked counting sort, no global atomics ----------------
__global__ __launch_bounds__(256) void p1_kernel(const int* __restrict__ dsts,
                                                 int* __restrict__ hist) {
  __shared__ int cnt[NBUCK];
  for (int j = threadIdx.x; j < NBUCK; j += 256) cnt[j] = 0;
  __syncthreads();
  int e0 = blockIdx.x * EPB;
  int e1 = min(e0 + EPB, NNZ_ALL);
  for (int e = e0 + threadIdx.x; e < e1; e += 256) {
    int li = edge_layer(e);
    int gcol = c_out_off[li] + dsts[e];
    atomicAdd(&cnt[gcol >> 7], 1);
  }
  __syncthreads();
  for (int j = threadIdx.x; j < NBUCK; j += 256) hist[j * NBLK + blockIdx.x] = cnt[j];
}

__global__ void scanA_kernel(const int* __restrict__ hist, int* __restrict__ start,
                             int* __restrict__ bsums) {
  __shared__ int sh[256];
  int t = threadIdx.x;
  int i = blockIdx.x * 256 + t;
  int v = (i < NSCAN) ? hist[i] : 0;
  sh[t] = v;
  __syncthreads();
  for (int o = 1; o < 256; o <<= 1) {
    int add = (t >= o) ? sh[t - o] : 0;
    __syncthreads();
    sh[t] += add;
    __syncthreads();
  }
  if (i < NSCAN) start[i] = sh[t] - v;
  if (t == 255) bsums[blockIdx.x] = sh[255];
}

__global__ void scanB_kernel(int* __restrict__ bsums) {
  __shared__ int sh[512];
  int t = threadIdx.x;
  int v = (t < NSB) ? bsums[t] : 0;
  sh[t] = v;
  __syncthreads();
  for (int o = 1; o < 512; o <<= 1) {
    int add = (t >= o) ? sh[t - o] : 0;
    __syncthreads();
    sh[t] += add;
    __syncthreads();
  }
  if (t < NSB) bsums[t] = sh[t] - v;
}

__global__ void scanC_kernel(int* __restrict__ start, const int* __restrict__ bsums) {
  int i = blockIdx.x * 256 + threadIdx.x;
  if (i < NSCAN) start[i] += bsums[blockIdx.x];
}

// p3: place edges into private (block,bucket) staging sub-ranges via LDS cursors.
__global__ __launch_bounds__(256) void p3_kernel(
    const int* __restrict__ dsts, const int* __restrict__ srcs,
    const float* __restrict__ wmu, const float* __restrict__ wls,
    const int* __restrict__ start, int2* __restrict__ staging, float* __restrict__ out_kl) {
  __shared__ int cur[NBUCK];
  for (int j = threadIdx.x; j < NBUCK; j += 256) cur[j] = start[j * NBLK + blockIdx.x];
  __syncthreads();
  int e0 = blockIdx.x * EPB;
  int e1 = min(e0 + EPB, NNZ_ALL);
  float kl = 0.f;
  for (int e = e0 + threadIdx.x; e < e1; e += 256) {
    int li = edge_layer(e);
    int gcol = c_out_off[li] + dsts[e];
    float m = wmu[e], l = wls[e];
    kl += expf(2.f * l) + m * m - 1.f - 2.f * l;
    int pos = atomicAdd(&cur[gcol >> 7], 1);
    staging[pos] = make_int2(__float_as_int(m), (srcs[e] << 7) | (gcol & 127));
  }
#pragma unroll
  for (int o = 32; o > 0; o >>= 1) kl += __shfl_down(kl, o, 64);
  __shared__ float sh[4];
  if ((threadIdx.x & 63) == 0) sh[threadIdx.x >> 6] = kl;
  __syncthreads();
  if (threadIdx.x == 0) atomicAdd(out_kl, 0.5f * (sh[0] + sh[1] + sh[2] + sh[3]));
}

// finalize: per bucket, count columns, write ptr[], reorder staging -> rec {src, w}
__global__ __launch_bounds__(256) void fin_kernel(const int* __restrict__ start,
                                                  const int2* __restrict__ staging,
                                                  int2* __restrict__ rec, int* __restrict__ ptr) {
  int b = blockIdx.x;
  int base = start[b * NBLK];
  int end = (b + 1 < NBUCK) ? start[(b + 1) * NBLK] : NNZ_ALL;
  int colbase = b << 7;
  int ncols = min(128, OUT_ALL - colbase);
  __shared__ int cnt[128], sc[128], cur[128];
  int t = threadIdx.x;
  if (t < 128) cnt[t] = 0;
  __syncthreads();
  for (int i = base + t; i < end; i += 256) atomicAdd(&cnt[staging[i].y & 127], 1);
  __syncthreads();
  if (t < 128) sc[t] = cnt[t];
  __syncthreads();
  for (int o = 1; o < 128; o <<= 1) {
    int add = (t < 128 && t >= o) ? sc[t - o] : 0;
    __syncthreads();
    if (t < 128) sc[t] += add;
    __syncthreads();
  }
  if (t < 128) {
    int excl = base + sc[t] - cnt[t];
    cur[t] = excl;
    if (t < ncols) ptr[colbase + t] = excl;
  }
  if (b == NBUCK - 1 && t == 0) ptr[OUT_ALL] = NNZ_ALL;
  __syncthreads();
  for (int i = base + t; i < end; i += 256) {
    int2 v = staging[i];
    int p = atomicAdd(&cur[v.y & 127], 1);
    rec[p] = make_int2(v.y >> 7, v.x);
  }
}

// ---------------- pool layer (sparse gather + bias only), fp16 h ----------------
__global__ __launch_bounds__(128) void pool_kernel(
    const __half* __restrict__ hin, __half* __restrict__ hout,
    const int* __restrict__ ptr, const int2* __restrict__ rec,
    const float* __restrict__ bias, int col_base) {
  const int d = blockIdx.x;
  const int t = threadIdx.x;
  if (t >= 100) return;
  const int g = col_base + d;
  int e0 = ptr[g], e1 = ptr[g + 1];
  const __half2* __restrict__ hin2 = (const __half2*)hin;
  float bb = bias[g];
  float a0 = bb, a1 = bb;
  int e = e0;
  for (; e + 2 <= e1; e += 2) {
    int2 rA = rec[e], rB = rec[e + 1];
    float wA = __int_as_float(rA.y), wB = __int_as_float(rB.y);
    float2 hA = __half22float2(hin2[rA.x * 100 + t]);
    float2 hB = __half22float2(hin2[rB.x * 100 + t]);
    a0 = fmaf(hA.x, wA, a0); a1 = fmaf(hA.y, wA, a1);
    a0 = fmaf(hB.x, wB, a0); a1 = fmaf(hB.y, wB, a1);
  }
  if (e < e1) {
    int2 rA = rec[e];
    float wA = __int_as_float(rA.y);
    float2 hA = __half22float2(hin2[rA.x * 100 + t]);
    a0 = fmaf(hA.x, wA, a0); a1 = fmaf(hA.y, wA, a1);
  }
  ((__half2*)hout)[d * 100 + t] = __float22half2_rn(make_float2(a0, a1));
}

// ---------------- lin layer fused with BN + ReLU + dropout, fp16 h ----------------
__global__ __launch_bounds__(128) void lin_bn_drop_kernel(
    const __half* __restrict__ hin, __half* __restrict__ hout,
    const int* __restrict__ ptr, const int2* __restrict__ rec,
    const float* __restrict__ bias, const float* __restrict__ gamma, const float* __restrict__ beta,
    int col_base, int bn_base, int S, uint32_t k0, uint32_t k1) {
  const int d = blockIdx.x;
  const int t = threadIdx.x;
  const int g = col_base + d;
  const int e0 = ptr[g], e1 = ptr[g + 1];
  const __half2* __restrict__ hin2 = (const __half2*)hin;
  float a0 = 0.f, a1 = 0.f;
  if (t < 100) {
    int e = e0;
    for (; e + 2 <= e1; e += 2) {
      int2 rA = rec[e], rB = rec[e + 1];
      float wA = __int_as_float(rA.y), wB = __int_as_float(rB.y);
      float2 hA = __half22float2(hin2[rA.x * 100 + t]);
      float2 hB = __half22float2(hin2[rB.x * 100 + t]);
      a0 = fmaf(hA.x, wA, a0); a1 = fmaf(hA.y, wA, a1);
      a0 = fmaf(hB.x, wB, a0); a1 = fmaf(hB.y, wB, a1);
    }
    if (e < e1) {
      int2 rA = rec[e];
      float wA = __int_as_float(rA.y);
      float2 hA = __half22float2(hin2[rA.x * 100 + t]);
      a0 = fmaf(hA.x, wA, a0); a1 = fmaf(hA.y, wA, a1);
    }
    float bb = bias[g];
    a0 += bb; a1 += bb;
  }
  float s = a0 + a1;
  float q = a0 * a0 + a1 * a1;
#pragma unroll
  for (int o = 32; o > 0; o >>= 1) { s += __shfl_down(s, o, 64); q += __shfl_down(q, o, 64); }
  __shared__ float shs[2], shq[2];
  if ((t & 63) == 0) { shs[t >> 6] = s; shq[t >> 6] = q; }
  __syncthreads();
  float sum = shs[0] + shs[1];
  float ssq = shq[0] + shq[1];
  float m = sum * (1.0f / 200.0f);
  float v = ssq * (1.0f / 200.0f) - m * m;
  if (v < 0.f) v = 0.f;
  float rstd = 1.0f / sqrtf(v + 1e-5f);
  if (t < 100) {
    float ga = gamma[bn_base + d], be = beta[bn_base + d];
    float y0 = fmaf((a0 - m) * rstd, ga, be);
    float y1 = fmaf((a1 - m) * rstd, ga, be);
    y0 = y0 > 0.f ? y0 : 0.f;
    y1 = y1 > 0.f ? y1 : 0.f;
    uint32_t i0 = (uint32_t)((2 * t) * S + d);
    float r0 = jax_uniform01(k0, k1, i0);
    float r1 = jax_uniform01(k0, k1, i0 + (uint32_t)S);
    y0 = (r0 < 0.9f) ? y0 * (1.0f / 0.9f) : 0.f;
    y1 = (r1 < 0.9f) ? y1 * (1.0f / 0.9f) : 0.f;
    ((__half2*)hout)[d * 100 + t] = __float22half2_rn(make_float2(y0, y1));
  }
}

// ---------------- final lin + plain BN, fp16 in, fp32 row-major out ----------------
__global__ __launch_bounds__(128) void final_bn_kernel(
    const __half* __restrict__ hin, float* __restrict__ out,
    const int* __restrict__ ptr, const int2* __restrict__ rec,
    const float* __restrict__ bias, int col_base) {
  const int d = blockIdx.x;
  const int t = threadIdx.x;
  const int g = col_base + d;
  const int e0 = ptr[g], e1 = ptr[g + 1];
  const __half2* __restrict__ hin2 = (const __half2*)hin;
  float a0 = 0.f, a1 = 0.f;
  if (t < 100) {
    for (int e = e0; e < e1; ++e) {
      int2 rA = rec[e];
      float wA = __int_as_float(rA.y);
      float2 hA = __half22float2(hin2[rA.x * 100 + t]);
      a0 = fmaf(hA.x, wA, a0); a1 = fmaf(hA.y, wA, a1);
    }
    float bb = bias[g];
    a0 += bb; a1 += bb;
  }
  float s = a0 + a1;
  float q = a0 * a0 + a1 * a1;
#pragma unroll
  for (int o = 32; o > 0; o >>= 1) { s += __shfl_down(s, o, 64); q += __shfl_down(q, o, 64); }
  __shared__ float shs[2], shq[2];
  if ((t & 63) == 0) { shs[t >> 6] = s; shq[t >> 6] = q; }
  __syncthreads();
  float sum = shs[0] + shs[1];
  float ssq = shq[0] + shq[1];
  float m = sum * (1.0f / 200.0f);
  float v = ssq * (1.0f / 200.0f) - m * m;
  if (v < 0.f) v = 0.f;
  float rstd = 1.0f / sqrtf(v + 1e-5f);
  if (t < 100) {
    out[(2 * t) * 469 + d]     = (a0 - m) * rstd;
    out[(2 * t + 1) * 469 + d] = (a1 - m) * rstd;
  }
}

extern "C" void kernel_launch(void* const* d_in, const int* in_sizes, int n_in,
                              void* d_out, int out_size, void* d_ws, size_t ws_size,
                              hipStream_t stream) {
  const float* x     = (const float*)d_in[0];
  const int*   edges = (const int*)d_in[1];
  const float* wmu   = (const float*)d_in[2];
  const float* wls   = (const float*)d_in[3];
  const float* bias  = (const float*)d_in[4];
  const float* gamma = (const float*)d_in[5];
  const float* beta  = (const float*)d_in[6];
  float* out = (float*)d_out;
  const int* srcs = edges;
  const int* dsts = edges + NNZ_ALL;

  char* p = (char*)d_ws;
  auto alloc = [&](size_t bytes) { char* r = p; p += (bytes + 255) & ~(size_t)255; return r; };
  __half* A      = (__half*)alloc((size_t)6000000 * 2);   // 30000 cols x 200, fp16
  __half* Bf     = (__half*)alloc((size_t)6000000 * 2);
  __half* C      = (__half*)alloc((size_t)3000000 * 2);
  int*   ptr     = (int*)alloc((size_t)(OUT_ALL + 1) * 4);
  int*   hist    = (int*)alloc((size_t)NSCAN * 4);
  int*   start   = (int*)alloc((size_t)NSCAN * 4);
  int*   bsums   = (int*)alloc((size_t)512 * 4);
  int2*  staging = (int2*)alloc((size_t)NNZ_ALL * 8);
  int2*  rec     = (int2*)alloc((size_t)NNZ_ALL * 8);

  // stage dropout keys: fold_in(key(1234), 100+st) = threefry2x32((0,1234),(0,100+st))
  uint32_t k0s[6], k1s[6];
  for (int st = 0; st < 6; ++st) {
    uint32_t a = 0u, b = (uint32_t)(100 + st);
    tf2x32(0u, 1234u, a, b);
    k0s[st] = a; k1s[st] = b;
  }

  transpose_kernel<<<dim3(938, 7), dim3(32, 8), 0, stream>>>(x, A, out + KL_IDX);
  p1_kernel<<<NBLK, 256, 0, stream>>>(dsts, hist);
  scanA_kernel<<<NSB, 256, 0, stream>>>(hist, start, bsums);
  scanB_kernel<<<1, 512, 0, stream>>>(bsums);
  scanC_kernel<<<NSB, 256, 0, stream>>>(start, bsums);
  p3_kernel<<<NBLK, 256, 0, stream>>>(dsts, srcs, wmu, wls, start, staging, out + KL_IDX);
  fin_kernel<<<NBUCK, 256, 0, stream>>>(start, staging, rec, ptr);

  const int S[7]        = {30000, 15000, 7500, 3750, 1875, 938, 469};
  const int OUT_OFF[14] = {0, 30000, 45000, 60000, 67500, 75000, 78750,
                           82500, 84375, 86250, 87188, 88126, 88595, 89064};
  const int BN_OFF[7]   = {0, 30000, 45000, 52500, 56250, 58125, 59063};

  lin_bn_drop_kernel<<<30000, 128, 0, stream>>>(A, Bf, ptr, rec, bias, gamma, beta,
                                                OUT_OFF[0], BN_OFF[0], S[0], k0s[0], k1s[0]);
  __half* cur = Bf;
  __half* alt = A;
  for (int st = 1; st <= 5; ++st) {
    int li_p = 2 * st - 1, li_l = 2 * st;
    pool_kernel<<<S[st], 128, 0, stream>>>(cur, C, ptr, rec, bias, OUT_OFF[li_p]);
    lin_bn_drop_kernel<<<S[st], 128, 0, stream>>>(C, alt, ptr, rec, bias, gamma, beta,
                                                  OUT_OFF[li_l], BN_OFF[st], S[st],
                                                  k0s[st], k1s[st]);
    __half* tmp = cur; cur = alt; alt = tmp;
  }
  pool_kernel<<<469, 128, 0, stream>>>(cur, C, ptr, rec, bias, OUT_OFF[11]);
  final_bn_kernel<<<469, 128, 0, stream>>>(C, out, ptr, rec, bias, OUT_OFF[12]);
}

// Round 8
// 305.816 us; speedup vs baseline: 1.4387x; 1.0282x over previous
//
#include <hip/hip_runtime.h>
#include <hip/hip_fp16.h>
#include <cstdint>
#include <cstddef>

#define B_SZ    200
#define NNZ_ALL 1070638
#define OUT_ALL 89064
#define NL      13
#define NBUCK   696    // ceil(OUT_ALL/128) slot-space buckets of 128 columns
#define EPB     8192   // edges per block in p1/p3
#define NBLK    131    // ceil(NNZ_ALL/EPB)
#define NSCAN   91176  // NBUCK*NBLK
#define NSB     357    // ceil(NSCAN/256)
#define KL_IDX  93800  // 200*469, KL scalar position in d_out

__constant__ int c_nnz_off[NL + 1] = {0, 480000, 540000, 780000, 810000, 930000, 945000,
                                      1005000, 1012500, 1042500, 1046250, 1061258, 1063134, 1070638};
__constant__ int c_out_off[NL + 1] = {0, 30000, 45000, 60000, 67500, 75000, 78750,
                                      82500, 84375, 86250, 87188, 88126, 88595, 89064};

// ---------------- threefry2x32 (matches jax._src.prng) ----------------
__host__ __device__ inline void tf2x32(uint32_t k0, uint32_t k1, uint32_t& x0, uint32_t& x1) {
  uint32_t ks2 = k0 ^ k1 ^ 0x1BD11BDAu;
  x0 += k0; x1 += k1;
#define TF_ROT(v, d) (((v) << (d)) | ((v) >> (32 - (d))))
#define TF_R4(a, b, c, dd)                                   \
  { x0 += x1; x1 = TF_ROT(x1, a);  x1 ^= x0;                 \
    x0 += x1; x1 = TF_ROT(x1, b);  x1 ^= x0;                 \
    x0 += x1; x1 = TF_ROT(x1, c);  x1 ^= x0;                 \
    x0 += x1; x1 = TF_ROT(x1, dd); x1 ^= x0; }
  TF_R4(13, 15, 26, 6);  x0 += k1;  x1 += ks2 + 1u;
  TF_R4(17, 29, 16, 24); x0 += ks2; x1 += k0  + 2u;
  TF_R4(13, 15, 26, 6);  x0 += k0;  x1 += k1  + 3u;
  TF_R4(17, 29, 16, 24); x0 += k1;  x1 += ks2 + 4u;
  TF_R4(13, 15, 26, 6);  x0 += ks2; x1 += k0  + 5u;
#undef TF_R4
#undef TF_ROT
}

// partitionable threefry random bits for 32-bit: bits_i = o0 ^ o1, counter i (hi=0)
__device__ inline float jax_uniform01(uint32_t k0, uint32_t k1, uint32_t i) {
  uint32_t x0 = 0u, x1 = i;
  tf2x32(k0, k1, x0, x1);
  uint32_t bits = x0 ^ x1;
  return __uint_as_float((bits >> 9) | 0x3f800000u) - 1.0f;
}

// ---------------- transpose x (200 x 30000 fp32 row-major) -> xt (fp16 col-major, stride 200)
// also zeroes the KL accumulator slot in d_out
__global__ void transpose_kernel(const float* __restrict__ x, __half* __restrict__ xt,
                                 float* __restrict__ out_kl) {
  if (blockIdx.x == 0 && blockIdx.y == 0 && threadIdx.x == 0 && threadIdx.y == 0)
    out_kl[0] = 0.0f;
  __shared__ float tile[32][33];
  int s0 = blockIdx.x * 32;
  int b0 = blockIdx.y * 32;
#pragma unroll
  for (int j = 0; j < 4; ++j) {
    int b = b0 + threadIdx.y + j * 8;
    int s = s0 + threadIdx.x;
    if (b < B_SZ && s < 30000) tile[threadIdx.y + j * 8][threadIdx.x] = x[b * 30000 + s];
  }
  __syncthreads();
#pragma unroll
  for (int j = 0; j < 4; ++j) {
    int s = s0 + threadIdx.y + j * 8;
    int b = b0 + threadIdx.x;
    if (b < B_SZ && s < 30000) xt[s * B_SZ + b] = __float2half(tile[threadIdx.x][threadIdx.y + j * 8]);
  }
}

__device__ inline int edge_layer(int e) {
  int li = 0;
#pragma unroll
  for (int j = 1; j < NL; ++j) li += (e >= c_nnz_off[j]) ? 1 : 0;
  return li;
}

// ---------------- CSR build: chunked counting sort, no global atomics ----------------
__global__ __launch_bounds__(256) void p1_kernel(const int* __restrict__ dsts,
                                                 int* __restrict__ hist) {
  __shared__ int cnt[NBUCK];
  for (int j = threadIdx.x; j < NBUCK; j += 256) cnt[j] = 0;
  __syncthreads();
  int e0 = blockIdx.x * EPB;
  int e1 = min(e0 + EPB, NNZ_ALL);
  for (int e = e0 + threadIdx.x; e < e1; e += 256) {
    int li = edge_layer(e);
    int gcol = c_out_off[li] + dsts[e];
    atomicAdd(&cnt[gcol >> 7], 1);
  }
  __syncthreads();
  for (int j = threadIdx.x; j < NBUCK; j += 256) hist[j * NBLK + blockIdx.x] = cnt[j];
}

__global__ void scanA_kernel(const int* __restrict__ hist, int* __restrict__ start,
                             int* __restrict__ bsums) {
  __shared__ int sh[256];
  int t = threadIdx.x;
  int i = blockIdx.x * 256 + t;
  int v = (i < NSCAN) ? hist[i] : 0;
  sh[t] = v;
  __syncthreads();
  for (int o = 1; o < 256; o <<= 1) {
    int add = (t >= o) ? sh[t - o] : 0;
    __syncthreads();
    sh[t] += add;
    __syncthreads();
  }
  if (i < NSCAN) start[i] = sh[t] - v;
  if (t == 255) bsums[blockIdx.x] = sh[255];
}

__global__ void scanB_kernel(int* __restrict__ bsums) {
  __shared__ int sh[512];
  int t = threadIdx.x;
  int v = (t < NSB) ? bsums[t] : 0;
  sh[t] = v;
  __syncthreads();
  for (int o = 1; o < 512; o <<= 1) {
    int add = (t >= o) ? sh[t - o] : 0;
    __syncthreads();
    sh[t] += add;
    __syncthreads();
  }
  if (t < NSB) bsums[t] = sh[t] - v;
}

__global__ void scanC_kernel(int* __restrict__ start, const int* __restrict__ bsums) {
  int i = blockIdx.x * 256 + threadIdx.x;
  if (i < NSCAN) start[i] += bsums[blockIdx.x];
}

// p3: place edges into private (block,bucket) staging sub-ranges via LDS cursors.
__global__ __launch_bounds__(256) void p3_kernel(
    const int* __restrict__ dsts, const int* __restrict__ srcs,
    const float* __restrict__ wmu, const float* __restrict__ wls,
    const int* __restrict__ start, int2* __restrict__ staging, float* __restrict__ out_kl) {
  __shared__ int cur[NBUCK];
  for (int j = threadIdx.x; j < NBUCK; j += 256) cur[j] = start[j * NBLK + blockIdx.x];
  __syncthreads();
  int e0 = blockIdx.x * EPB;
  int e1 = min(e0 + EPB, NNZ_ALL);
  float kl = 0.f;
  for (int e = e0 + threadIdx.x; e < e1; e += 256) {
    int li = edge_layer(e);
    int gcol = c_out_off[li] + dsts[e];
    float m = wmu[e], l = wls[e];
    kl += expf(2.f * l) + m * m - 1.f - 2.f * l;
    int pos = atomicAdd(&cur[gcol >> 7], 1);
    staging[pos] = make_int2(__float_as_int(m), (srcs[e] << 7) | (gcol & 127));
  }
#pragma unroll
  for (int o = 32; o > 0; o >>= 1) kl += __shfl_down(kl, o, 64);
  __shared__ float sh[4];
  if ((threadIdx.x & 63) == 0) sh[threadIdx.x >> 6] = kl;
  __syncthreads();
  if (threadIdx.x == 0) atomicAdd(out_kl, 0.5f * (sh[0] + sh[1] + sh[2] + sh[3]));
}

// finalize: per bucket, count columns, write ptr[], reorder staging -> rec {src*100, w}
__global__ __launch_bounds__(256) void fin_kernel(const int* __restrict__ start,
                                                  const int2* __restrict__ staging,
                                                  int2* __restrict__ rec, int* __restrict__ ptr) {
  int b = blockIdx.x;
  int base = start[b * NBLK];
  int end = (b + 1 < NBUCK) ? start[(b + 1) * NBLK] : NNZ_ALL;
  int colbase = b << 7;
  int ncols = min(128, OUT_ALL - colbase);
  __shared__ int cnt[128], sc[128], cur[128];
  int t = threadIdx.x;
  if (t < 128) cnt[t] = 0;
  __syncthreads();
  for (int i = base + t; i < end; i += 256) atomicAdd(&cnt[staging[i].y & 127], 1);
  __syncthreads();
  if (t < 128) sc[t] = cnt[t];
  __syncthreads();
  for (int o = 1; o < 128; o <<= 1) {
    int add = (t < 128 && t >= o) ? sc[t - o] : 0;
    __syncthreads();
    if (t < 128) sc[t] += add;
    __syncthreads();
  }
  if (t < 128) {
    int excl = base + sc[t] - cnt[t];
    cur[t] = excl;
    if (t < ncols) ptr[colbase + t] = excl;
  }
  if (b == NBUCK - 1 && t == 0) ptr[OUT_ALL] = NNZ_ALL;
  __syncthreads();
  for (int i = base + t; i < end; i += 256) {
    int2 v = staging[i];
    int p = atomicAdd(&cur[v.y & 127], 1);
    rec[p] = make_int2((v.y >> 7) * 100, v.x);   // pre-multiplied half2 index
  }
}

// ---------------- gather core: unroll-4, 4 loads in flight ----------------
__device__ inline void gather_edges(const __half2* __restrict__ hin2, const int2* __restrict__ rec,
                                    int e0, int e1, int t, float& a0, float& a1) {
  int e = e0;
  for (; e + 4 <= e1; e += 4) {
    int2 r0 = rec[e], r1 = rec[e + 1], r2 = rec[e + 2], r3 = rec[e + 3];
    __half2 h0 = hin2[r0.x + t];
    __half2 h1 = hin2[r1.x + t];
    __half2 h2 = hin2[r2.x + t];
    __half2 h3 = hin2[r3.x + t];
    float w0 = __int_as_float(r0.y), w1 = __int_as_float(r1.y);
    float w2 = __int_as_float(r2.y), w3 = __int_as_float(r3.y);
    float2 f0 = __half22float2(h0), f1 = __half22float2(h1);
    float2 f2 = __half22float2(h2), f3 = __half22float2(h3);
    a0 = fmaf(f0.x, w0, a0); a1 = fmaf(f0.y, w0, a1);
    a0 = fmaf(f1.x, w1, a0); a1 = fmaf(f1.y, w1, a1);
    a0 = fmaf(f2.x, w2, a0); a1 = fmaf(f2.y, w2, a1);
    a0 = fmaf(f3.x, w3, a0); a1 = fmaf(f3.y, w3, a1);
  }
  for (; e < e1; ++e) {
    int2 r0 = rec[e];
    float w0 = __int_as_float(r0.y);
    float2 f0 = __half22float2(hin2[r0.x + t]);
    a0 = fmaf(f0.x, w0, a0); a1 = fmaf(f0.y, w0, a1);
  }
}

// ---------------- pool layer (sparse gather + bias only), fp16 h ----------------
__global__ __launch_bounds__(128) void pool_kernel(
    const __half* __restrict__ hin, __half* __restrict__ hout,
    const int* __restrict__ ptr, const int2* __restrict__ rec,
    const float* __restrict__ bias, int col_base) {
  const int d = blockIdx.x;
  const int t = threadIdx.x;
  if (t >= 100) return;
  const int g = col_base + d;
  int e0 = ptr[g], e1 = ptr[g + 1];
  const __half2* __restrict__ hin2 = (const __half2*)hin;
  float bb = bias[g];
  float a0 = bb, a1 = bb;
  gather_edges(hin2, rec, e0, e1, t, a0, a1);
  ((__half2*)hout)[d * 100 + t] = __float22half2_rn(make_float2(a0, a1));
}

// ---------------- lin layer fused with BN + ReLU + dropout, fp16 h ----------------
__global__ __launch_bounds__(128) void lin_bn_drop_kernel(
    const __half* __restrict__ hin, __half* __restrict__ hout,
    const int* __restrict__ ptr, const int2* __restrict__ rec,
    const float* __restrict__ bias, const float* __restrict__ gamma, const float* __restrict__ beta,
    int col_base, int bn_base, int S, uint32_t k0, uint32_t k1) {
  const int d = blockIdx.x;
  const int t = threadIdx.x;
  const int g = col_base + d;
  const int e0 = ptr[g], e1 = ptr[g + 1];
  const __half2* __restrict__ hin2 = (const __half2*)hin;
  float a0 = 0.f, a1 = 0.f;
  if (t < 100) {
    gather_edges(hin2, rec, e0, e1, t, a0, a1);
    float bb = bias[g];
    a0 += bb; a1 += bb;
  }
  float s = a0 + a1;
  float q = a0 * a0 + a1 * a1;
#pragma unroll
  for (int o = 32; o > 0; o >>= 1) { s += __shfl_down(s, o, 64); q += __shfl_down(q, o, 64); }
  __shared__ float shs[2], shq[2];
  if ((t & 63) == 0) { shs[t >> 6] = s; shq[t >> 6] = q; }
  __syncthreads();
  float sum = shs[0] + shs[1];
  float ssq = shq[0] + shq[1];
  float m = sum * (1.0f / 200.0f);
  float v = ssq * (1.0f / 200.0f) - m * m;
  if (v < 0.f) v = 0.f;
  float rstd = 1.0f / sqrtf(v + 1e-5f);
  if (t < 100) {
    float ga = gamma[bn_base + d], be = beta[bn_base + d];
    float y0 = fmaf((a0 - m) * rstd, ga, be);
    float y1 = fmaf((a1 - m) * rstd, ga, be);
    y0 = y0 > 0.f ? y0 : 0.f;
    y1 = y1 > 0.f ? y1 : 0.f;
    uint32_t i0 = (uint32_t)((2 * t) * S + d);
    float r0 = jax_uniform01(k0, k1, i0);
    float r1 = jax_uniform01(k0, k1, i0 + (uint32_t)S);
    y0 = (r0 < 0.9f) ? y0 * (1.0f / 0.9f) : 0.f;
    y1 = (r1 < 0.9f) ? y1 * (1.0f / 0.9f) : 0.f;
    ((__half2*)hout)[d * 100 + t] = __float22half2_rn(make_float2(y0, y1));
  }
}

// ---------------- final lin + plain BN, fp16 in, fp32 row-major out ----------------
__global__ __launch_bounds__(128) void final_bn_kernel(
    const __half* __restrict__ hin, float* __restrict__ out,
    const int* __restrict__ ptr, const int2* __restrict__ rec,
    const float* __restrict__ bias, int col_base) {
  const int d = blockIdx.x;
  const int t = threadIdx.x;
  const int g = col_base + d;
  const int e0 = ptr[g], e1 = ptr[g + 1];
  const __half2* __restrict__ hin2 = (const __half2*)hin;
  float a0 = 0.f, a1 = 0.f;
  if (t < 100) {
    gather_edges(hin2, rec, e0, e1, t, a0, a1);
    float bb = bias[g];
    a0 += bb; a1 += bb;
  }
  float s = a0 + a1;
  float q = a0 * a0 + a1 * a1;
#pragma unroll
  for (int o = 32; o > 0; o >>= 1) { s += __shfl_down(s, o, 64); q += __shfl_down(q, o, 64); }
  __shared__ float shs[2], shq[2];
  if ((t & 63) == 0) { shs[t >> 6] = s; shq[t >> 6] = q; }
  __syncthreads();
  float sum = shs[0] + shs[1];
  float ssq = shq[0] + shq[1];
  float m = sum * (1.0f / 200.0f);
  float v = ssq * (1.0f / 200.0f) - m * m;
  if (v < 0.f) v = 0.f;
  float rstd = 1.0f / sqrtf(v + 1e-5f);
  if (t < 100) {
    out[(2 * t) * 469 + d]     = (a0 - m) * rstd;
    out[(2 * t + 1) * 469 + d] = (a1 - m) * rstd;
  }
}

extern "C" void kernel_launch(void* const* d_in, const int* in_sizes, int n_in,
                              void* d_out, int out_size, void* d_ws, size_t ws_size,
                              hipStream_t stream) {
  const float* x     = (const float*)d_in[0];
  const int*   edges = (const int*)d_in[1];
  const float* wmu   = (const float*)d_in[2];
  const float* wls   = (const float*)d_in[3];
  const float* bias  = (const float*)d_in[4];
  const float* gamma = (const float*)d_in[5];
  const float* beta  = (const float*)d_in[6];
  float* out = (float*)d_out;
  const int* srcs = edges;
  const int* dsts = edges + NNZ_ALL;

  char* p = (char*)d_ws;
  auto alloc = [&](size_t bytes) { char* r = p; p += (bytes + 255) & ~(size_t)255; return r; };
  __half* A      = (__half*)alloc((size_t)6000000 * 2);   // 30000 cols x 200, fp16
  __half* Bf     = (__half*)alloc((size_t)6000000 * 2);
  __half* C      = (__half*)alloc((size_t)3000000 * 2);
  int*   ptr     = (int*)alloc((size_t)(OUT_ALL + 1) * 4);
  int*   hist    = (int*)alloc((size_t)NSCAN * 4);
  int*   start   = (int*)alloc((size_t)NSCAN * 4);
  int*   bsums   = (int*)alloc((size_t)512 * 4);
  int2*  staging = (int2*)alloc((size_t)NNZ_ALL * 8);
  int2*  rec     = (int2*)alloc((size_t)NNZ_ALL * 8);

  // stage dropout keys: fold_in(key(1234), 100+st) = threefry2x32((0,1234),(0,100+st))
  uint32_t k0s[6], k1s[6];
  for (int st = 0; st < 6; ++st) {
    uint32_t a = 0u, b = (uint32_t)(100 + st);
    tf2x32(0u, 1234u, a, b);
    k0s[st] = a; k1s[st] = b;
  }

  transpose_kernel<<<dim3(938, 7), dim3(32, 8), 0, stream>>>(x, A, out + KL_IDX);
  p1_kernel<<<NBLK, 256, 0, stream>>>(dsts, hist);
  scanA_kernel<<<NSB, 256, 0, stream>>>(hist, start, bsums);
  scanB_kernel<<<1, 512, 0, stream>>>(bsums);
  scanC_kernel<<<NSB, 256, 0, stream>>>(start, bsums);
  p3_kernel<<<NBLK, 256, 0, stream>>>(dsts, srcs, wmu, wls, start, staging, out + KL_IDX);
  fin_kernel<<<NBUCK, 256, 0, stream>>>(start, staging, rec, ptr);

  const int S[7]        = {30000, 15000, 7500, 3750, 1875, 938, 469};
  const int OUT_OFF[14] = {0, 30000, 45000, 60000, 67500, 75000, 78750,
                           82500, 84375, 86250, 87188, 88126, 88595, 89064};
  const int BN_OFF[7]   = {0, 30000, 45000, 52500, 56250, 58125, 59063};

  lin_bn_drop_kernel<<<30000, 128, 0, stream>>>(A, Bf, ptr, rec, bias, gamma, beta,
                                                OUT_OFF[0], BN_OFF[0], S[0], k0s[0], k1s[0]);
  __half* cur = Bf;
  __half* alt = A;
  for (int st = 1; st <= 5; ++st) {
    int li_p = 2 * st - 1, li_l = 2 * st;
    pool_kernel<<<S[st], 128, 0, stream>>>(cur, C, ptr, rec, bias, OUT_OFF[li_p]);
    lin_bn_drop_kernel<<<S[st], 128, 0, stream>>>(C, alt, ptr, rec, bias, gamma, beta,
                                                  OUT_OFF[li_l], BN_OFF[st], S[st],
                                                  k0s[st], k1s[st]);
    __half* tmp = cur; cur = alt; alt = tmp;
  }
  pool_kernel<<<469, 128, 0, stream>>>(cur, C, ptr, rec, bias, OUT_OFF[11]);
  final_bn_kernel<<<469, 128, 0, stream>>>(C, out, ptr, rec, bias, OUT_OFF[12]);
}

// Round 9
// 297.677 us; speedup vs baseline: 1.4780x; 1.0273x over previous
//
#include <hip/hip_runtime.h>
#include <hip/hip_fp16.h>
#include <cstdint>
#include <cstddef>

#define B_SZ    200
#define NNZ_ALL 1070638
#define OUT_ALL 89064
#define NL      13
#define NBUCK   696    // ceil(OUT_ALL/128) slot-space buckets of 128 columns
#define EPB     8192   // edges per block in p1/p3
#define NBLK    131    // ceil(NNZ_ALL/EPB)
#define NSCAN   91176  // NBUCK*NBLK
#define NSB     357    // ceil(NSCAN/256)
#define KL_IDX  93800  // 200*469, KL scalar position in d_out

__constant__ int c_nnz_off[NL + 1] = {0, 480000, 540000, 780000, 810000, 930000, 945000,
                                      1005000, 1012500, 1042500, 1046250, 1061258, 1063134, 1070638};
__constant__ int c_out_off[NL + 1] = {0, 30000, 45000, 60000, 67500, 75000, 78750,
                                      82500, 84375, 86250, 87188, 88126, 88595, 89064};

// ---------------- threefry2x32 (matches jax._src.prng) ----------------
__host__ __device__ inline void tf2x32(uint32_t k0, uint32_t k1, uint32_t& x0, uint32_t& x1) {
  uint32_t ks2 = k0 ^ k1 ^ 0x1BD11BDAu;
  x0 += k0; x1 += k1;
#define TF_ROT(v, d) (((v) << (d)) | ((v) >> (32 - (d))))
#define TF_R4(a, b, c, dd)                                   \
  { x0 += x1; x1 = TF_ROT(x1, a);  x1 ^= x0;                 \
    x0 += x1; x1 = TF_ROT(x1, b);  x1 ^= x0;                 \
    x0 += x1; x1 = TF_ROT(x1, c);  x1 ^= x0;                 \
    x0 += x1; x1 = TF_ROT(x1, dd); x1 ^= x0; }
  TF_R4(13, 15, 26, 6);  x0 += k1;  x1 += ks2 + 1u;
  TF_R4(17, 29, 16, 24); x0 += ks2; x1 += k0  + 2u;
  TF_R4(13, 15, 26, 6);  x0 += k0;  x1 += k1  + 3u;
  TF_R4(17, 29, 16, 24); x0 += k1;  x1 += ks2 + 4u;
  TF_R4(13, 15, 26, 6);  x0 += ks2; x1 += k0  + 5u;
#undef TF_R4
#undef TF_ROT
}

// partitionable threefry random bits for 32-bit: bits_i = o0 ^ o1, counter i (hi=0)
__device__ inline float jax_uniform01(uint32_t k0, uint32_t k1, uint32_t i) {
  uint32_t x0 = 0u, x1 = i;
  tf2x32(k0, k1, x0, x1);
  uint32_t bits = x0 ^ x1;
  return __uint_as_float((bits >> 9) | 0x3f800000u) - 1.0f;
}

// ---------------- transpose x (200 x 30000 fp32 row-major) -> xt (fp16 col-major, stride 200)
// also zeroes the KL accumulator slot in d_out
__global__ void transpose_kernel(const float* __restrict__ x, __half* __restrict__ xt,
                                 float* __restrict__ out_kl) {
  if (blockIdx.x == 0 && blockIdx.y == 0 && threadIdx.x == 0 && threadIdx.y == 0)
    out_kl[0] = 0.0f;
  __shared__ float tile[32][33];
  int s0 = blockIdx.x * 32;
  int b0 = blockIdx.y * 32;
#pragma unroll
  for (int j = 0; j < 4; ++j) {
    int b = b0 + threadIdx.y + j * 8;
    int s = s0 + threadIdx.x;
    if (b < B_SZ && s < 30000) tile[threadIdx.y + j * 8][threadIdx.x] = x[b * 30000 + s];
  }
  __syncthreads();
#pragma unroll
  for (int j = 0; j < 4; ++j) {
    int s = s0 + threadIdx.y + j * 8;
    int b = b0 + threadIdx.x;
    if (b < B_SZ && s < 30000) xt[s * B_SZ + b] = __float2half(tile[threadIdx.x][threadIdx.y + j * 8]);
  }
}

__device__ inline int edge_layer(int e) {
  int li = 0;
#pragma unroll
  for (int j = 1; j < NL; ++j) li += (e >= c_nnz_off[j]) ? 1 : 0;
  return li;
}

// ---------------- CSR build: chunked counting sort, no global atomics ----------------
__global__ __launch_bounds__(256) void p1_kernel(const int* __restrict__ dsts,
                                                 int* __restrict__ hist) {
  __shared__ int cnt[NBUCK];
  for (int j = threadIdx.x; j < NBUCK; j += 256) cnt[j] = 0;
  __syncthreads();
  int e0 = blockIdx.x * EPB;
  int e1 = min(e0 + EPB, NNZ_ALL);
  for (int e = e0 + threadIdx.x; e < e1; e += 256) {
    int li = edge_layer(e);
    int gcol = c_out_off[li] + dsts[e];
    atomicAdd(&cnt[gcol >> 7], 1);
  }
  __syncthreads();
  for (int j = threadIdx.x; j < NBUCK; j += 256) hist[j * NBLK + blockIdx.x] = cnt[j];
}

__global__ void scanA_kernel(const int* __restrict__ hist, int* __restrict__ start,
                             int* __restrict__ bsums) {
  __shared__ int sh[256];
  int t = threadIdx.x;
  int i = blockIdx.x * 256 + t;
  int v = (i < NSCAN) ? hist[i] : 0;
  sh[t] = v;
  __syncthreads();
  for (int o = 1; o < 256; o <<= 1) {
    int add = (t >= o) ? sh[t - o] : 0;
    __syncthreads();
    sh[t] += add;
    __syncthreads();
  }
  if (i < NSCAN) start[i] = sh[t] - v;
  if (t == 255) bsums[blockIdx.x] = sh[255];
}

__global__ void scanB_kernel(int* __restrict__ bsums) {
  __shared__ int sh[512];
  int t = threadIdx.x;
  int v = (t < NSB) ? bsums[t] : 0;
  sh[t] = v;
  __syncthreads();
  for (int o = 1; o < 512; o <<= 1) {
    int add = (t >= o) ? sh[t - o] : 0;
    __syncthreads();
    sh[t] += add;
    __syncthreads();
  }
  if (t < NSB) bsums[t] = sh[t] - v;
}

__global__ void scanC_kernel(int* __restrict__ start, const int* __restrict__ bsums) {
  int i = blockIdx.x * 256 + threadIdx.x;
  if (i < NSCAN) start[i] += bsums[blockIdx.x];
}

// p3: place edges into private (block,bucket) staging sub-ranges via LDS cursors.
__global__ __launch_bounds__(256) void p3_kernel(
    const int* __restrict__ dsts, const int* __restrict__ srcs,
    const float* __restrict__ wmu, const float* __restrict__ wls,
    const int* __restrict__ start, int2* __restrict__ staging, float* __restrict__ out_kl) {
  __shared__ int cur[NBUCK];
  for (int j = threadIdx.x; j < NBUCK; j += 256) cur[j] = start[j * NBLK + blockIdx.x];
  __syncthreads();
  int e0 = blockIdx.x * EPB;
  int e1 = min(e0 + EPB, NNZ_ALL);
  float kl = 0.f;
  for (int e = e0 + threadIdx.x; e < e1; e += 256) {
    int li = edge_layer(e);
    int gcol = c_out_off[li] + dsts[e];
    float m = wmu[e], l = wls[e];
    kl += expf(2.f * l) + m * m - 1.f - 2.f * l;
    int pos = atomicAdd(&cur[gcol >> 7], 1);
    staging[pos] = make_int2(__float_as_int(m), (srcs[e] << 7) | (gcol & 127));
  }
#pragma unroll
  for (int o = 32; o > 0; o >>= 1) kl += __shfl_down(kl, o, 64);
  __shared__ float sh[4];
  if ((threadIdx.x & 63) == 0) sh[threadIdx.x >> 6] = kl;
  __syncthreads();
  if (threadIdx.x == 0) atomicAdd(out_kl, 0.5f * (sh[0] + sh[1] + sh[2] + sh[3]));
}

// finalize: per bucket, count columns, write ptr[], reorder staging -> rec {src*50, w}
__global__ __launch_bounds__(256) void fin_kernel(const int* __restrict__ start,
                                                  const int2* __restrict__ staging,
                                                  int2* __restrict__ rec, int* __restrict__ ptr) {
  int b = blockIdx.x;
  int base = start[b * NBLK];
  int end = (b + 1 < NBUCK) ? start[(b + 1) * NBLK] : NNZ_ALL;
  int colbase = b << 7;
  int ncols = min(128, OUT_ALL - colbase);
  __shared__ int cnt[128], sc[128], cur[128];
  int t = threadIdx.x;
  if (t < 128) cnt[t] = 0;
  __syncthreads();
  for (int i = base + t; i < end; i += 256) atomicAdd(&cnt[staging[i].y & 127], 1);
  __syncthreads();
  if (t < 128) sc[t] = cnt[t];
  __syncthreads();
  for (int o = 1; o < 128; o <<= 1) {
    int add = (t < 128 && t >= o) ? sc[t - o] : 0;
    __syncthreads();
    if (t < 128) sc[t] += add;
    __syncthreads();
  }
  if (t < 128) {
    int excl = base + sc[t] - cnt[t];
    cur[t] = excl;
    if (t < ncols) ptr[colbase + t] = excl;
  }
  if (b == NBUCK - 1 && t == 0) ptr[OUT_ALL] = NNZ_ALL;
  __syncthreads();
  for (int i = base + t; i < end; i += 256) {
    int2 v = staging[i];
    int p = atomicAdd(&cur[v.y & 127], 1);
    rec[p] = make_int2((v.y >> 7) * 50, v.x);   // pre-multiplied uint2 (4-half) index
  }
}

// ---------------- gather core: wave-per-column, chunk-16 pipeline ----------------
// thread t<50 handles batch elements 4t..4t+3 (one uint2 = 4 halves per edge)
__device__ inline void gather_wave(const uint2* __restrict__ hin4, const int2* __restrict__ rec,
                                   int e0, int e1, int t,
                                   float& a0, float& a1, float& a2, float& a3) {
  int e = e0;
  while (e + 16 <= e1) {
    int2 r[16];
    uint2 h[16];
#pragma unroll
    for (int i = 0; i < 16; ++i) r[i] = rec[e + i];
#pragma unroll
    for (int i = 0; i < 16; ++i) h[i] = hin4[r[i].x + t];
#pragma unroll
    for (int i = 0; i < 16; ++i) {
      float w = __int_as_float(r[i].y);
      __half2 lo = *reinterpret_cast<__half2*>(&h[i].x);
      __half2 hi = *reinterpret_cast<__half2*>(&h[i].y);
      float2 f01 = __half22float2(lo);
      float2 f23 = __half22float2(hi);
      a0 = fmaf(f01.x, w, a0); a1 = fmaf(f01.y, w, a1);
      a2 = fmaf(f23.x, w, a2); a3 = fmaf(f23.y, w, a3);
    }
    e += 16;
  }
  while (e + 4 <= e1) {
    int2 r[4];
    uint2 h[4];
#pragma unroll
    for (int i = 0; i < 4; ++i) r[i] = rec[e + i];
#pragma unroll
    for (int i = 0; i < 4; ++i) h[i] = hin4[r[i].x + t];
#pragma unroll
    for (int i = 0; i < 4; ++i) {
      float w = __int_as_float(r[i].y);
      __half2 lo = *reinterpret_cast<__half2*>(&h[i].x);
      __half2 hi = *reinterpret_cast<__half2*>(&h[i].y);
      float2 f01 = __half22float2(lo);
      float2 f23 = __half22float2(hi);
      a0 = fmaf(f01.x, w, a0); a1 = fmaf(f01.y, w, a1);
      a2 = fmaf(f23.x, w, a2); a3 = fmaf(f23.y, w, a3);
    }
    e += 4;
  }
  for (; e < e1; ++e) {
    int2 r = rec[e];
    float w = __int_as_float(r.y);
    uint2 h = hin4[r.x + t];
    __half2 lo = *reinterpret_cast<__half2*>(&h.x);
    __half2 hi = *reinterpret_cast<__half2*>(&h.y);
    float2 f01 = __half22float2(lo);
    float2 f23 = __half22float2(hi);
    a0 = fmaf(f01.x, w, a0); a1 = fmaf(f01.y, w, a1);
    a2 = fmaf(f23.x, w, a2); a3 = fmaf(f23.y, w, a3);
  }
}

__device__ inline uint2 pack4(float a0, float a1, float a2, float a3) {
  __half2 p0 = __float22half2_rn(make_float2(a0, a1));
  __half2 p1 = __float22half2_rn(make_float2(a2, a3));
  uint2 u;
  u.x = *reinterpret_cast<unsigned int*>(&p0);
  u.y = *reinterpret_cast<unsigned int*>(&p1);
  return u;
}

// ---------------- pool layer (sparse gather + bias only), wave-per-column ----------------
__global__ __launch_bounds__(256) void pool_kernel(
    const __half* __restrict__ hin, __half* __restrict__ hout,
    const int* __restrict__ ptr, const int2* __restrict__ rec,
    const float* __restrict__ bias, int col_base, int S) {
  const int w = threadIdx.x >> 6;
  const int t = threadIdx.x & 63;
  const int d = blockIdx.x * 4 + w;
  if (d >= S || t >= 50) return;
  const int g = col_base + d;
  int e0 = ptr[g], e1 = ptr[g + 1];
  const uint2* __restrict__ hin4 = (const uint2*)hin;
  float bb = bias[g];
  float a0 = bb, a1 = bb, a2 = bb, a3 = bb;
  gather_wave(hin4, rec, e0, e1, t, a0, a1, a2, a3);
  ((uint2*)hout)[d * 50 + t] = pack4(a0, a1, a2, a3);
}

// ---------------- lin layer fused with BN + ReLU + dropout, wave-per-column ----------------
__global__ __launch_bounds__(256) void lin_bn_drop_kernel(
    const __half* __restrict__ hin, __half* __restrict__ hout,
    const int* __restrict__ ptr, const int2* __restrict__ rec,
    const float* __restrict__ bias, const float* __restrict__ gamma, const float* __restrict__ beta,
    int col_base, int bn_base, int S, uint32_t k0, uint32_t k1) {
  const int w = threadIdx.x >> 6;
  const int t = threadIdx.x & 63;
  const int d = blockIdx.x * 4 + w;
  if (d >= S) return;
  const int g = col_base + d;
  const int e0 = ptr[g], e1 = ptr[g + 1];
  const uint2* __restrict__ hin4 = (const uint2*)hin;
  float a0 = 0.f, a1 = 0.f, a2 = 0.f, a3 = 0.f;
  if (t < 50) {
    gather_wave(hin4, rec, e0, e1, t, a0, a1, a2, a3);
    float bb = bias[g];
    a0 += bb; a1 += bb; a2 += bb; a3 += bb;
  }
  // wave-local butterfly reduction over 200 values (lanes >=50 contribute 0)
  float s = a0 + a1 + a2 + a3;
  float q = a0 * a0 + a1 * a1 + a2 * a2 + a3 * a3;
#pragma unroll
  for (int o = 32; o > 0; o >>= 1) { s += __shfl_xor(s, o, 64); q += __shfl_xor(q, o, 64); }
  float m = s * (1.0f / 200.0f);
  float v = q * (1.0f / 200.0f) - m * m;
  if (v < 0.f) v = 0.f;
  float rstd = 1.0f / sqrtf(v + 1e-5f);
  if (t < 50) {
    float ga = gamma[bn_base + d], be = beta[bn_base + d];
    float y0 = fmaf((a0 - m) * rstd, ga, be);
    float y1 = fmaf((a1 - m) * rstd, ga, be);
    float y2 = fmaf((a2 - m) * rstd, ga, be);
    float y3 = fmaf((a3 - m) * rstd, ga, be);
    y0 = y0 > 0.f ? y0 : 0.f;
    y1 = y1 > 0.f ? y1 : 0.f;
    y2 = y2 > 0.f ? y2 : 0.f;
    y3 = y3 > 0.f ? y3 : 0.f;
    uint32_t i0 = (uint32_t)((4 * t) * S + d);
    float r0 = jax_uniform01(k0, k1, i0);
    float r1 = jax_uniform01(k0, k1, i0 + (uint32_t)S);
    float r2 = jax_uniform01(k0, k1, i0 + (uint32_t)(2 * S));
    float r3 = jax_uniform01(k0, k1, i0 + (uint32_t)(3 * S));
    y0 = (r0 < 0.9f) ? y0 * (1.0f / 0.9f) : 0.f;
    y1 = (r1 < 0.9f) ? y1 * (1.0f / 0.9f) : 0.f;
    y2 = (r2 < 0.9f) ? y2 * (1.0f / 0.9f) : 0.f;
    y3 = (r3 < 0.9f) ? y3 * (1.0f / 0.9f) : 0.f;
    ((uint2*)hout)[d * 50 + t] = pack4(y0, y1, y2, y3);
  }
}

// ---------------- final lin + plain BN, fp16 in, fp32 row-major out ----------------
__global__ __launch_bounds__(256) void final_bn_kernel(
    const __half* __restrict__ hin, float* __restrict__ out,
    const int* __restrict__ ptr, const int2* __restrict__ rec,
    const float* __restrict__ bias, int col_base) {
  const int w = threadIdx.x >> 6;
  const int t = threadIdx.x & 63;
  const int d = blockIdx.x * 4 + w;
  if (d >= 469) return;
  const int g = col_base + d;
  const int e0 = ptr[g], e1 = ptr[g + 1];
  const uint2* __restrict__ hin4 = (const uint2*)hin;
  float a0 = 0.f, a1 = 0.f, a2 = 0.f, a3 = 0.f;
  if (t < 50) {
    gather_wave(hin4, rec, e0, e1, t, a0, a1, a2, a3);
    float bb = bias[g];
    a0 += bb; a1 += bb; a2 += bb; a3 += bb;
  }
  float s = a0 + a1 + a2 + a3;
  float q = a0 * a0 + a1 * a1 + a2 * a2 + a3 * a3;
#pragma unroll
  for (int o = 32; o > 0; o >>= 1) { s += __shfl_xor(s, o, 64); q += __shfl_xor(q, o, 64); }
  float m = s * (1.0f / 200.0f);
  float v = q * (1.0f / 200.0f) - m * m;
  if (v < 0.f) v = 0.f;
  float rstd = 1.0f / sqrtf(v + 1e-5f);
  if (t < 50) {
    out[(4 * t) * 469 + d]     = (a0 - m) * rstd;
    out[(4 * t + 1) * 469 + d] = (a1 - m) * rstd;
    out[(4 * t + 2) * 469 + d] = (a2 - m) * rstd;
    out[(4 * t + 3) * 469 + d] = (a3 - m) * rstd;
  }
}

extern "C" void kernel_launch(void* const* d_in, const int* in_sizes, int n_in,
                              void* d_out, int out_size, void* d_ws, size_t ws_size,
                              hipStream_t stream) {
  const float* x     = (const float*)d_in[0];
  const int*   edges = (const int*)d_in[1];
  const float* wmu   = (const float*)d_in[2];
  const float* wls   = (const float*)d_in[3];
  const float* bias  = (const float*)d_in[4];
  const float* gamma = (const float*)d_in[5];
  const float* beta  = (const float*)d_in[6];
  float* out = (float*)d_out;
  const int* srcs = edges;
  const int* dsts = edges + NNZ_ALL;

  char* p = (char*)d_ws;
  auto alloc = [&](size_t bytes) { char* r = p; p += (bytes + 255) & ~(size_t)255; return r; };
  __half* A      = (__half*)alloc((size_t)6000000 * 2);   // 30000 cols x 200, fp16
  __half* Bf     = (__half*)alloc((size_t)6000000 * 2);
  __half* C      = (__half*)alloc((size_t)3000000 * 2);
  int*   ptr     = (int*)alloc((size_t)(OUT_ALL + 1) * 4);
  int*   hist    = (int*)alloc((size_t)NSCAN * 4);
  int*   start   = (int*)alloc((size_t)NSCAN * 4);
  int*   bsums   = (int*)alloc((size_t)512 * 4);
  int2*  staging = (int2*)alloc((size_t)NNZ_ALL * 8);
  int2*  rec     = (int2*)alloc((size_t)NNZ_ALL * 8);

  // stage dropout keys: fold_in(key(1234), 100+st) = threefry2x32((0,1234),(0,100+st))
  uint32_t k0s[6], k1s[6];
  for (int st = 0; st < 6; ++st) {
    uint32_t a = 0u, b = (uint32_t)(100 + st);
    tf2x32(0u, 1234u, a, b);
    k0s[st] = a; k1s[st] = b;
  }

  transpose_kernel<<<dim3(938, 7), dim3(32, 8), 0, stream>>>(x, A, out + KL_IDX);
  p1_kernel<<<NBLK, 256, 0, stream>>>(dsts, hist);
  scanA_kernel<<<NSB, 256, 0, stream>>>(hist, start, bsums);
  scanB_kernel<<<1, 512, 0, stream>>>(bsums);
  scanC_kernel<<<NSB, 256, 0, stream>>>(start, bsums);
  p3_kernel<<<NBLK, 256, 0, stream>>>(dsts, srcs, wmu, wls, start, staging, out + KL_IDX);
  fin_kernel<<<NBUCK, 256, 0, stream>>>(start, staging, rec, ptr);

  const int S[7]        = {30000, 15000, 7500, 3750, 1875, 938, 469};
  const int OUT_OFF[14] = {0, 30000, 45000, 60000, 67500, 75000, 78750,
                           82500, 84375, 86250, 87188, 88126, 88595, 89064};
  const int BN_OFF[7]   = {0, 30000, 45000, 52500, 56250, 58125, 59063};

  lin_bn_drop_kernel<<<7500, 256, 0, stream>>>(A, Bf, ptr, rec, bias, gamma, beta,
                                               OUT_OFF[0], BN_OFF[0], S[0], k0s[0], k1s[0]);
  __half* cur = Bf;
  __half* alt = A;
  for (int st = 1; st <= 5; ++st) {
    int li_p = 2 * st - 1, li_l = 2 * st;
    int nb = (S[st] + 3) / 4;
    pool_kernel<<<nb, 256, 0, stream>>>(cur, C, ptr, rec, bias, OUT_OFF[li_p], S[st]);
    lin_bn_drop_kernel<<<nb, 256, 0, stream>>>(C, alt, ptr, rec, bias, gamma, beta,
                                               OUT_OFF[li_l], BN_OFF[st], S[st],
                                               k0s[st], k1s[st]);
    __half* tmp = cur; cur = alt; alt = tmp;
  }
  pool_kernel<<<118, 256, 0, stream>>>(cur, C, ptr, rec, bias, OUT_OFF[11], 469);
  final_bn_kernel<<<118, 256, 0, stream>>>(C, out, ptr, rec, bias, OUT_OFF[12]);
}